// Round 10
// baseline (3411.671 us; speedup 1.0000x reference)
//
#include <hip/hip_runtime.h>
#include <hip/hip_bf16.h>

typedef __hip_bfloat16 bf16;
typedef __bf16 bfv8 __attribute__((ext_vector_type(8)));
typedef float f32x4 __attribute__((ext_vector_type(4)));

#define BB 4
#define HH 128
#define WWI 128
#define NN 16384      // HH*WWI
#define CC 256
#define LL 4
#define NHEADS 8
#define DHD 32
#define GG 64
#define INNERC 256    // NHEADS*DHD
#define HIDD 1024
#define SPLIT 32      // split-K blocks per (b,h) in slice_st
#define SSP 16        // points per block in slice_softmax

__device__ __forceinline__ float b2f(bf16 x) { return __bfloat162float(x); }
__device__ __forceinline__ bf16 f2b(float x) { return __float2bfloat16(x); }
__device__ __forceinline__ float us2f(unsigned short v) {
  return __uint_as_float(((unsigned)v) << 16);
}
__device__ __forceinline__ bfv8 ldg8(const bf16* p) { return *(const bfv8*)(const void*)p; }

__device__ __forceinline__ float wave_sum(float v) {
#pragma unroll
  for (int off = 32; off > 0; off >>= 1) v += __shfl_down(v, off, 64);
  return v;
}

__device__ __forceinline__ float gelu_exact(float x) {
  return 0.5f * x * (1.0f + erff(x * 0.70710678118654752f));
}

// ---------- batched transpose+cast: src fp32 [T][R][Cm] -> dst bf16 [T][Cm][R] ----------
__global__ void transpose_cast_kernel(const float* __restrict__ src, bf16* __restrict__ dst,
                                      int R, int Cm) {
  __shared__ float tile[32][33];
  int tb = blockIdx.z;
  const float* s = src + (size_t)tb * R * Cm;
  bf16* d = dst + (size_t)tb * R * Cm;
  int c0 = blockIdx.x * 32, r0 = blockIdx.y * 32;
  int tx = threadIdx.x & 31, ty = threadIdx.x >> 5;  // 32 x 8
  for (int rr = ty; rr < 32; rr += 8) {
    int r = r0 + rr, c = c0 + tx;
    tile[rr][tx] = (r < R && c < Cm) ? s[(size_t)r * Cm + c] : 0.f;
  }
  __syncthreads();
  for (int cc = ty; cc < 32; cc += 8) {
    int c = c0 + cc, r = r0 + tx;
    if (c < Cm && r < R) d[(size_t)c * R + r] = f2b(tile[tx][cc]);
  }
}

// ---------- LayerNorm over C=256 per point; block = 256 threads ----------
__global__ void ln_kernel(const float* __restrict__ x, const float* __restrict__ w,
                          const float* __restrict__ b, bf16* __restrict__ out) {
  int pp = blockIdx.x;
  int t = threadIdx.x;
  float v = x[(size_t)pp * CC + t];
  float s = wave_sum(v);
  float sq = wave_sum(v * v);
  __shared__ float ls[4], lq[4];
  int wid = t >> 6, lane = t & 63;
  if (lane == 0) { ls[wid] = s; lq[wid] = sq; }
  __syncthreads();
  float tot = ls[0] + ls[1] + ls[2] + ls[3];
  float totq = lq[0] + lq[1] + lq[2] + lq[3];
  float mean = tot * (1.0f / CC);
  float var = totq * (1.0f / CC) - mean * mean;
  float rstd = rsqrtf(var + 1e-5f);
  float o = (v - mean) * rstd * w[t] + b[t];
  out[(size_t)pp * CC + t] = f2b(o);
}

// ---------- 3x3 conv as implicit MFMA GEMM (round-7 proven: B staged via LDS) ----------
__global__ __launch_bounds__(256, 2) void conv_mfma_kernel(
    const bf16* __restrict__ xln, const bf16* __restrict__ wt,
    const float* __restrict__ bias, bf16* __restrict__ out) {
  __shared__ __align__(16) unsigned short As[3 * 130 * 64];
  __shared__ __align__(16) unsigned short Bsm[128 * 64];
  int bid = blockIdx.x;
  int nh = bid & 1;
  int h = (bid >> 1) & 127;
  int b = bid >> 8;
  int t = threadIdx.x, lane = t & 63, wid = t >> 6;
  int wm = (wid >> 1) * 64, wn = (wid & 1) * 64;
  int l15 = lane & 15, l4 = lane >> 4;
  f32x4 acc[4][4];
#pragma unroll
  for (int mi = 0; mi < 4; ++mi)
#pragma unroll
    for (int ni = 0; ni < 4; ++ni) acc[mi][ni] = (f32x4){0.f, 0.f, 0.f, 0.f};
  const bf16* xbase = xln + (size_t)b * NN * CC;

  for (int q = 0; q < 4; ++q) {
    __syncthreads();
    for (int u = t; u < 3120; u += 256) {
      int jp = u & 7;
      int pc = u >> 3;
      int r = pc / 130, cl = pc - r * 130;
      int j = jp ^ (cl & 7);
      int gr = h + r - 1, gc = cl - 1;
      uint4 v = make_uint4(0u, 0u, 0u, 0u);
      if ((unsigned)gr < 128u && (unsigned)gc < 128u)
        v = *(const uint4*)(xbase + ((size_t)(gr * WWI + gc)) * CC + q * 64 + j * 8);
      *(uint4*)(&As[(size_t)u * 8]) = v;
    }
    for (int tap = 0; tap < 9; ++tap) {
      if (tap > 0) __syncthreads();
      {
        const bf16* wsrc = wt + ((size_t)tap * 256 + nh * 128) * 256 + q * 64;
#pragma unroll
        for (int i = 0; i < 4; ++i) {
          int u = t + (i << 8);
          int n = u >> 3, jp = u & 7, j = jp ^ (n & 7);
          uint4 v = *(const uint4*)(wsrc + (size_t)n * 256 + j * 8);
          *(uint4*)(&Bsm[(size_t)u * 8]) = v;
        }
      }
      __syncthreads();
      int ky = tap / 3, kx = tap - ky * 3;
#pragma unroll
      for (int s = 0; s < 2; ++s) {
        bfv8 af[4], bfr[4];
#pragma unroll
        for (int mi = 0; mi < 4; ++mi) {
          int cl = wm + mi * 16 + l15 + kx;
          af[mi] = *(const bfv8*)(&As[((size_t)(ky * 130 + cl)) * 64 +
                                      (((s * 4 + l4) ^ (cl & 7)) << 3)]);
        }
#pragma unroll
        for (int ni = 0; ni < 4; ++ni) {
          int rn = wn + ni * 16 + l15;
          bfr[ni] = *(const bfv8*)(&Bsm[(size_t)rn * 64 + (((s * 4 + l4) ^ (rn & 7)) << 3)]);
        }
#pragma unroll
        for (int mi = 0; mi < 4; ++mi)
#pragma unroll
          for (int ni = 0; ni < 4; ++ni)
            acc[mi][ni] = __builtin_amdgcn_mfma_f32_16x16x32_bf16(af[mi], bfr[ni], acc[mi][ni], 0, 0, 0);
      }
    }
  }
  int colB = wn + l15;
  int rowB = wm + l4 * 4;
#pragma unroll
  for (int ni = 0; ni < 4; ++ni) {
    int oc = nh * 128 + colB + ni * 16;
    float bv = bias[oc];
#pragma unroll
    for (int mi = 0; mi < 4; ++mi) {
#pragma unroll
      for (int r = 0; r < 4; ++r) {
        int pix = rowB + mi * 16 + r;
        out[((size_t)(b * NN + h * WWI + pix)) * CC + oc] = f2b(acc[mi][ni][r] + bv);
      }
    }
  }
}

// ---------- z-batched MFMA GEMM, outf += acc + bias (round-7 proven: A+B via LDS) ----------
__global__ __launch_bounds__(256, 2) void gemm_acc_kernel(
    const bf16* __restrict__ A, const bf16* __restrict__ BT,
    const float* __restrict__ bias, float* __restrict__ outf,
    int M, int N, int K, size_t strideAz, size_t strideBz, size_t strideOz) {
  A  += (size_t)blockIdx.z * strideAz;
  BT += (size_t)blockIdx.z * strideBz;
  __shared__ __align__(16) unsigned short As[128 * 64];
  __shared__ __align__(16) unsigned short Bsm[128 * 64];
  int m0 = blockIdx.x * 128, n0 = blockIdx.y * 128;
  int t = threadIdx.x, lane = t & 63, wid = t >> 6;
  int wm = (wid >> 1) * 64, wn = (wid & 1) * 64;
  int l15 = lane & 15, l4 = lane >> 4;
  f32x4 acc[4][4];
#pragma unroll
  for (int mi = 0; mi < 4; ++mi)
#pragma unroll
    for (int ni = 0; ni < 4; ++ni) acc[mi][ni] = (f32x4){0.f, 0.f, 0.f, 0.f};

  for (int kb = 0; kb < K; kb += 64) {
    __syncthreads();
    uint4 va[4], vb[4];
#pragma unroll
    for (int i = 0; i < 4; ++i) {
      int u = t + (i << 8);
      int row = u >> 3, j = (u & 7) ^ (row & 7);
      va[i] = *(const uint4*)(A + (size_t)(m0 + row) * K + kb + j * 8);
      vb[i] = *(const uint4*)(BT + (size_t)(n0 + row) * K + kb + j * 8);
    }
#pragma unroll
    for (int i = 0; i < 4; ++i) {
      int u = t + (i << 8);
      *(uint4*)(&As[(size_t)u * 8]) = va[i];
      *(uint4*)(&Bsm[(size_t)u * 8]) = vb[i];
    }
    __syncthreads();
#pragma unroll
    for (int s = 0; s < 2; ++s) {
      bfv8 af[4], bfr[4];
#pragma unroll
      for (int mi = 0; mi < 4; ++mi) {
        int row = wm + mi * 16 + l15;
        af[mi] = *(const bfv8*)(&As[(size_t)row * 64 + (((s * 4 + l4) ^ (row & 7)) << 3)]);
      }
#pragma unroll
      for (int ni = 0; ni < 4; ++ni) {
        int rn = wn + ni * 16 + l15;
        bfr[ni] = *(const bfv8*)(&Bsm[(size_t)rn * 64 + (((s * 4 + l4) ^ (rn & 7)) << 3)]);
      }
#pragma unroll
      for (int mi = 0; mi < 4; ++mi)
#pragma unroll
        for (int ni = 0; ni < 4; ++ni)
          acc[mi][ni] = __builtin_amdgcn_mfma_f32_16x16x32_bf16(af[mi], bfr[ni], acc[mi][ni], 0, 0, 0);
    }
  }
  int colB = n0 + wn + l15;
  int rowB = m0 + wm + l4 * 4;
#pragma unroll
  for (int ni = 0; ni < 4; ++ni) {
    int col = colB + ni * 16;
    float bv = bias[col];
#pragma unroll
    for (int mi = 0; mi < 4; ++mi) {
#pragma unroll
      for (int r = 0; r < 4; ++r) {
        int row = rowB + mi * 16 + r;
        outf[(size_t)blockIdx.z * strideOz + (size_t)row * N + col] += acc[mi][ni][r] + bv;
      }
    }
  }
}

// ---------- fused MLP: fx += gelu(xln@w1+b1)@w2+b2 ----------
// 1024 threads / 16 waves (4 waves/SIMD). A tile staged once in LDS; Hs double-buffered;
// W1/W2 fragments streamed from global (L2-hot). 1 barrier per hidden chunk.
__global__ __launch_bounds__(1024, 1) void mlp_fused_kernel(
    const bf16* __restrict__ xln, const bf16* __restrict__ w1t,
    const float* __restrict__ b1, const bf16* __restrict__ w2t,
    const float* __restrict__ b2, float* __restrict__ fx) {
  __shared__ __align__(16) unsigned short As[128 * 256];  // 64 KiB (per-64 XOR swizzle)
  __shared__ __align__(16) bf16 Hs[2][128 * 128];         // 64 KiB
  int m0 = blockIdx.x * 128;
  int t = threadIdx.x, lane = t & 63, wid = t >> 6;       // wid 0..15
  int l15 = lane & 15, q4 = lane >> 4;
  // GEMM1: 128x128 chunk as 4x4 waves of 32m x 32n
  int w1row = (wid & 3) * 32, w1col = (wid >> 2) * 32;
  // GEMM2: 128x256 as 4x4 waves of 32m x 64n
  int w2row = (wid & 3) * 32, w2col = (wid >> 2) * 64;

  // stage A (xln rows m0..m0+127, full K=256) — once
  const unsigned short* xg = (const unsigned short*)xln + (size_t)m0 * 256;
#pragma unroll
  for (int i = 0; i < 4; ++i) {
    int u = t + i * 1024;                 // 4096 vec writes
    int row = u >> 5, v = u & 31;
    int kb = v >> 3, jp = v & 7;
    uint4 val = ((const uint4*)xg)[u];
    ((uint4*)As)[row * 32 + kb * 8 + (jp ^ (row & 7))] = val;
  }
  __syncthreads();

  f32x4 accO[2][4];
#pragma unroll
  for (int mi = 0; mi < 2; ++mi)
#pragma unroll
    for (int ni = 0; ni < 4; ++ni) accO[mi][ni] = (f32x4){0.f, 0.f, 0.f, 0.f};

  for (int j = 0; j < 8; ++j) {           // hidden chunks of 128
    int hbase = j * 128;
    bf16* Hb = Hs[j & 1];
    f32x4 acc2[2][2];
#pragma unroll
    for (int mi = 0; mi < 2; ++mi)
#pragma unroll
      for (int nj = 0; nj < 2; ++nj) acc2[mi][nj] = (f32x4){0.f, 0.f, 0.f, 0.f};
    // ---- GEMM1: hidden chunk = A(LDS) @ W1(global)[:, hbase:hbase+128] ----
#pragma unroll
    for (int kb = 0; kb < 4; ++kb) {
#pragma unroll
      for (int ks = 0; ks < 2; ++ks) {
        int kgrp = ks * 4 + q4;
        bfv8 af[2], bfr[2];
#pragma unroll
        for (int mi = 0; mi < 2; ++mi) {
          int row = w1row + mi * 16 + l15;
          af[mi] = *(const bfv8*)(&As[row * 256 + kb * 64 + ((kgrp ^ (row & 7)) << 3)]);
        }
#pragma unroll
        for (int nj = 0; nj < 2; ++nj)
          bfr[nj] = ldg8(w1t + (size_t)(hbase + w1col + nj * 16 + l15) * 256 + kb * 64 + kgrp * 8);
#pragma unroll
        for (int mi = 0; mi < 2; ++mi)
#pragma unroll
          for (int nj = 0; nj < 2; ++nj)
            acc2[mi][nj] = __builtin_amdgcn_mfma_f32_16x16x32_bf16(af[mi], bfr[nj], acc2[mi][nj], 0, 0, 0);
      }
    }
    // ---- +b1, gelu, pack to Hb (bf16) ----
#pragma unroll
    for (int nj = 0; nj < 2; ++nj) {
      int coln = w1col + nj * 16 + l15;
      float bv = b1[hbase + coln];
      int half = coln >> 6, sub = (coln >> 3) & 7, lo = coln & 7;
#pragma unroll
      for (int mi = 0; mi < 2; ++mi) {
#pragma unroll
        for (int r = 0; r < 4; ++r) {
          int row = w1row + mi * 16 + q4 * 4 + r;
          float v = acc2[mi][nj][r] + bv;
          Hb[row * 128 + half * 64 + (((sub ^ (row & 7)) << 3) + lo)] = f2b(gelu_exact(v));
        }
      }
    }
    __syncthreads();                      // Hb visible; prior-buffer readers already past
    // ---- GEMM2: out += H(LDS) @ W2(global)[hbase:hbase+128, :] ----
#pragma unroll
    for (int kb2 = 0; kb2 < 2; ++kb2) {
#pragma unroll
      for (int ks = 0; ks < 2; ++ks) {
        int kgrp = ks * 4 + q4;
        bfv8 af[2], bfr[4];
#pragma unroll
        for (int mi = 0; mi < 2; ++mi) {
          int row = w2row + mi * 16 + l15;
          af[mi] = *(const bfv8*)(&Hb[row * 128 + kb2 * 64 + ((kgrp ^ (row & 7)) << 3)]);
        }
#pragma unroll
        for (int ni = 0; ni < 4; ++ni)
          bfr[ni] = ldg8(w2t + (size_t)(w2col + ni * 16 + l15) * 1024 + hbase + kb2 * 64 + kgrp * 8);
#pragma unroll
        for (int mi = 0; mi < 2; ++mi)
#pragma unroll
          for (int ni = 0; ni < 4; ++ni)
            accO[mi][ni] = __builtin_amdgcn_mfma_f32_16x16x32_bf16(af[mi], bfr[ni], accO[mi][ni], 0, 0, 0);
      }
    }
  }
  // ---- epilogue: fx += accO + b2 ----
#pragma unroll
  for (int ni = 0; ni < 4; ++ni) {
    int col = w2col + ni * 16 + l15;
    float bv = b2[col];
#pragma unroll
    for (int mi = 0; mi < 2; ++mi) {
#pragma unroll
      for (int r = 0; r < 4; ++r) {
        int row = m0 + w2row + mi * 16 + q4 * 4 + r;
        fx[(size_t)row * 256 + col] += accO[mi][ni][r] + bv;
      }
    }
  }
}

// ---------- slice logits + softmax over G; 16 points/block, weights in LDS ----------
__global__ __launch_bounds__(256) void slice_softmax_kernel(
    const bf16* __restrict__ xmid, const float* __restrict__ sw_w,
    const float* __restrict__ sw_b, const float* __restrict__ temp,
    bf16* __restrict__ swout) {
  __shared__ float wsm[32][64];     // 8 KiB  [d][g]
  __shared__ float xm[SSP][256];    // 16 KiB
  __shared__ float bias_s[64];
  __shared__ float rtc[8];
  int p0 = blockIdx.x * SSP;
  int t = threadIdx.x;
  for (int i = t; i < 2048; i += 256) wsm[i >> 6][i & 63] = sw_w[i];
  if (t < 64) bias_s[t] = sw_b[t];
  if (t < 8) {
    float x = temp[t];
    rtc[t] = 1.0f / fminf(fmaxf(x, 0.1f), 5.0f);
  }
  const unsigned short* xg = (const unsigned short*)xmid + (size_t)p0 * 256;
#pragma unroll
  for (int i2 = t; i2 < SSP * 32; i2 += 256) {
    uint4 v = ((const uint4*)xg)[i2];
    int p = i2 >> 5, c = (i2 & 31) << 3;
    xm[p][c + 0] = us2f((unsigned short)(v.x & 0xffff));
    xm[p][c + 1] = us2f((unsigned short)(v.x >> 16));
    xm[p][c + 2] = us2f((unsigned short)(v.y & 0xffff));
    xm[p][c + 3] = us2f((unsigned short)(v.y >> 16));
    xm[p][c + 4] = us2f((unsigned short)(v.z & 0xffff));
    xm[p][c + 5] = us2f((unsigned short)(v.z >> 16));
    xm[p][c + 6] = us2f((unsigned short)(v.w & 0xffff));
    xm[p][c + 7] = us2f((unsigned short)(v.w >> 16));
  }
  __syncthreads();
  int g = t & 63, pq = t >> 6;
  for (int pp2 = 0; pp2 < SSP / 4; ++pp2) {
    int p = pp2 * 4 + pq;
#pragma unroll
    for (int h = 0; h < NHEADS; ++h) {
      float acc = bias_s[g];
      const float* xr = &xm[p][h * 32];
#pragma unroll
      for (int d = 0; d < 32; ++d) acc += xr[d] * wsm[d][g];
      float logit = acc * rtc[h];
      float m = logit;
#pragma unroll
      for (int off = 32; off > 0; off >>= 1) m = fmaxf(m, __shfl_xor(m, off, 64));
      float e = __expf(logit - m);
      float s = e;
#pragma unroll
      for (int off = 32; off > 0; off >>= 1) s += __shfl_xor(s, off, 64);
      swout[(size_t)(p0 + p) * 512 + h * 64 + g] = f2b(e / s);
    }
  }
}

// ---------- slice reduce as split-K MFMA outer product ----------
__global__ __launch_bounds__(256) void slice_st_kernel(
    const bf16* __restrict__ fxmid, const bf16* __restrict__ sw,
    float* __restrict__ stp, float* __restrict__ normp) {
  __shared__ __align__(16) unsigned short sw_s[64 * 64];
  __shared__ __align__(16) unsigned short fx_s[32 * 64];
  __shared__ float npart[2][64];
  int split = blockIdx.x, h = blockIdx.y, b = blockIdx.z;
  int t = threadIdx.x, w = t >> 6, lane = t & 63;
  int l15 = lane & 15, q4 = lane >> 4;
  int ns0 = split * (NN / SPLIT);
  const int NT = (NN / SPLIT) / 64;
  f32x4 acc0 = {0.f, 0.f, 0.f, 0.f}, acc1 = {0.f, 0.f, 0.f, 0.f};
  float nacc = 0.f;
  const unsigned short* swg = (const unsigned short*)sw + (size_t)b * NN * 512 + h * 64;
  const unsigned short* fxg = (const unsigned short*)fxmid + (size_t)b * NN * 256 + h * 32;

  for (int kt = 0; kt < NT; ++kt) {
    int n0 = ns0 + kt * 64;
    __syncthreads();
    if (w < 2) {
      int g = lane;
#pragma unroll
      for (int i = 0; i < 4; ++i) {
        int j = w + 2 * i;
        const unsigned short* p = swg + (size_t)(n0 + j * 8) * 512 + g;
        unsigned short v0 = p[0],     v1 = p[512],  v2 = p[1024], v3 = p[1536];
        unsigned short v4 = p[2048],  v5 = p[2560], v6 = p[3072], v7 = p[3584];
        nacc += us2f(v0) + us2f(v1) + us2f(v2) + us2f(v3) +
                us2f(v4) + us2f(v5) + us2f(v6) + us2f(v7);
        uint4 pk = make_uint4((unsigned)v0 | ((unsigned)v1 << 16),
                              (unsigned)v2 | ((unsigned)v3 << 16),
                              (unsigned)v4 | ((unsigned)v5 << 16),
                              (unsigned)v6 | ((unsigned)v7 << 16));
        ((uint4*)sw_s)[g * 8 + (j ^ (g & 7))] = pk;
      }
    } else {
      int d = lane & 31, nh = lane >> 5, w3 = w - 2;
#pragma unroll
      for (int i = 0; i < 2; ++i) {
        int nbase = (w3 * 2 + i) * 16 + nh * 8;
        const unsigned short* p = fxg + (size_t)(n0 + nbase) * 256 + d;
        unsigned short v0 = p[0],    v1 = p[256],  v2 = p[512],  v3 = p[768];
        unsigned short v4 = p[1024], v5 = p[1280], v6 = p[1536], v7 = p[1792];
        uint4 pk = make_uint4((unsigned)v0 | ((unsigned)v1 << 16),
                              (unsigned)v2 | ((unsigned)v3 << 16),
                              (unsigned)v4 | ((unsigned)v5 << 16),
                              (unsigned)v6 | ((unsigned)v7 << 16));
        int u = nbase >> 3;
        ((uint4*)fx_s)[d * 8 + (u ^ (d & 7))] = pk;
      }
    }
    __syncthreads();
    int gg = w * 16 + l15;
    int d0 = l15, d1 = 16 + l15;
#pragma unroll
    for (int ks = 0; ks < 2; ++ks) {
      bfv8 af  = ((const bfv8*)sw_s)[gg * 8 + ((ks * 4 + q4) ^ (gg & 7))];
      bfv8 bf0 = ((const bfv8*)fx_s)[d0 * 8 + ((ks * 4 + q4) ^ (d0 & 7))];
      bfv8 bf1 = ((const bfv8*)fx_s)[d1 * 8 + ((ks * 4 + q4) ^ (d1 & 7))];
      acc0 = __builtin_amdgcn_mfma_f32_16x16x32_bf16(af, bf0, acc0, 0, 0, 0);
      acc1 = __builtin_amdgcn_mfma_f32_16x16x32_bf16(af, bf1, acc1, 0, 0, 0);
    }
  }
  if (w < 2) npart[w][lane] = nacc;
  __syncthreads();
  int bh = b * NHEADS + h;
  if (t < 64) normp[(size_t)split * (BB * NHEADS * GG) + bh * 64 + t] = npart[0][t] + npart[1][t];
  size_t base = ((size_t)split * (BB * NHEADS * GG) + bh * 64) * 32;
#pragma unroll
  for (int r = 0; r < 4; ++r) {
    int g = w * 16 + q4 * 4 + r;
    stp[base + (size_t)g * 32 + l15] = acc0[r];
    stp[base + (size_t)g * 32 + 16 + l15] = acc1[r];
  }
}

// ---------- attention over G=64 per (b,h); 256 threads; weights + reduction in LDS ----------
__global__ __launch_bounds__(256) void attn_kernel(
    const float* __restrict__ stp, const float* __restrict__ normp,
    const float* __restrict__ wq, const float* __restrict__ wk,
    const float* __restrict__ wv, float* __restrict__ ot) {
  __shared__ float wqs[32 * 32], wks[32 * 32], wvs[32 * 32];
  __shared__ float st[GG][DHD + 1];
  __shared__ float qq[GG][DHD + 1], kk[GG][DHD + 1], vv[GG][DHD + 1];
  __shared__ float pm[GG][GG + 1];
  __shared__ float nrm[GG];
  int bh = blockIdx.x;
  int t = threadIdx.x;
  ((float4*)wqs)[t] = ((const float4*)wq)[t];
  ((float4*)wks)[t] = ((const float4*)wk)[t];
  ((float4*)wvs)[t] = ((const float4*)wv)[t];
  if (t < 64) {
    float ns = 0.f;
    for (int s = 0; s < SPLIT; ++s) ns += normp[(size_t)s * (BB * NHEADS * GG) + bh * 64 + t];
    nrm[t] = 1.0f / (ns + 1e-5f);
  }
  __syncthreads();
#pragma unroll
  for (int i = 0; i < 8; ++i) {
    int idx = t + i * 256;
    int g = idx >> 5, d = idx & 31;
    float a = 0.f;
    for (int s = 0; s < SPLIT; ++s)
      a += stp[((size_t)s * (BB * NHEADS * GG) + bh * 64 + g) * 32 + d];
    st[g][d] = a * nrm[g];
  }
  __syncthreads();
#pragma unroll
  for (int i = 0; i < 8; ++i) {
    int idx = t + i * 256;
    int g = idx >> 5, d = idx & 31;
    float aq = 0.f, ak = 0.f, av = 0.f;
#pragma unroll
    for (int c = 0; c < 32; ++c) {
      float sv = st[g][c];
      aq += sv * wqs[c * 32 + d];
      ak += sv * wks[c * 32 + d];
      av += sv * wvs[c * 32 + d];
    }
    qq[g][d] = aq; kk[g][d] = ak; vv[g][d] = av;
  }
  __syncthreads();
  {
    int g = t >> 2, sub = t & 3;
    float sc[16];
    float m = -1e30f;
    const float scale = 0.17677669529663687f;
#pragma unroll
    for (int jj = 0; jj < 16; ++jj) {
      int j = sub * 16 + jj;
      float a = 0.f;
#pragma unroll
      for (int d = 0; d < 32; ++d) a += qq[g][d] * kk[j][d];
      a *= scale;
      sc[jj] = a;
      m = fmaxf(m, a);
    }
    m = fmaxf(m, __shfl_xor(m, 1, 64));
    m = fmaxf(m, __shfl_xor(m, 2, 64));
    float ssum = 0.f;
#pragma unroll
    for (int jj = 0; jj < 16; ++jj) { sc[jj] = __expf(sc[jj] - m); ssum += sc[jj]; }
    ssum += __shfl_xor(ssum, 1, 64);
    ssum += __shfl_xor(ssum, 2, 64);
    float rs = 1.0f / ssum;
#pragma unroll
    for (int jj = 0; jj < 16; ++jj) pm[g][sub * 16 + jj] = sc[jj] * rs;
  }
  __syncthreads();
#pragma unroll
  for (int i = 0; i < 8; ++i) {
    int idx = t + i * 256;
    int g = idx >> 5, d = idx & 31;
    float a = 0.f;
#pragma unroll
    for (int j = 0; j < GG; ++j) a += pm[g][j] * vv[j][d];
    ot[((size_t)bh * GG + g) * DHD + d] = a;
  }
}

// ---------- Wc^T[b][c][h*64+g] = sum_d ot[b,h,g,d] * wo[h*32+d, c]  (bf16 out) ----------
__global__ __launch_bounds__(256) void wc_kernel(const float* __restrict__ ot,
                                                 const float* __restrict__ wo,
                                                 bf16* __restrict__ wct) {
  __shared__ float ots[GG][DHD];   // 8 KiB
  int bh = blockIdx.x;             // b*8 + h
  int h = bh & 7, b = bh >> 3;
  int t = threadIdx.x;             // 256 = c
  for (int i = t; i < GG * DHD; i += 256) ots[i >> 5][i & 31] = ot[(size_t)bh * (GG * DHD) + i];
  float wol[DHD];
#pragma unroll
  for (int d = 0; d < DHD; ++d) wol[d] = wo[(size_t)(h * DHD + d) * CC + t];
  __syncthreads();
  bf16* dst = wct + ((size_t)b * CC + t) * (NHEADS * GG) + h * GG;
#pragma unroll 4
  for (int g = 0; g < GG; ++g) {
    float a = 0.f;
#pragma unroll
    for (int d = 0; d < DHD; ++d) a += wol[d] * ots[g][d];
    dst[g] = f2b(a);
  }
}

// ---------- final LN3 + head (C -> 4) ----------
__global__ void head_kernel(const float* __restrict__ fx, const float* __restrict__ w,
                            const float* __restrict__ b, const float* __restrict__ wout,
                            const float* __restrict__ bout, float* __restrict__ out) {
  int pp = blockIdx.x;
  int t = threadIdx.x;
  float v = fx[(size_t)pp * CC + t];
  float s = wave_sum(v);
  float sq = wave_sum(v * v);
  __shared__ float ls[4], lq[4];
  int wid = t >> 6, lane = t & 63;
  if (lane == 0) { ls[wid] = s; lq[wid] = sq; }
  __syncthreads();
  float tot = ls[0] + ls[1] + ls[2] + ls[3];
  float totq = lq[0] + lq[1] + lq[2] + lq[3];
  float mean = tot * (1.0f / CC);
  float var = totq * (1.0f / CC) - mean * mean;
  float rstd = rsqrtf(var + 1e-5f);
  float xn = (v - mean) * rstd * w[t] + b[t];
  __shared__ float xs[CC];
  xs[t] = xn;
  __syncthreads();
  if (t < 4) {
    float a = bout[t];
    for (int c = 0; c < CC; ++c) a += xs[c] * wout[c * 4 + t];
    out[(size_t)pp * 4 + t] = a;
  }
}

extern "C" void kernel_launch(void* const* d_in, const int* in_sizes, int n_in,
                              void* d_out, int out_size, void* d_ws, size_t ws_size,
                              hipStream_t stream) {
  const float* fx_in      = (const float*)d_in[0];
  const float* ln1_w      = (const float*)d_in[1];
  const float* ln1_b      = (const float*)d_in[2];
  const float* convx_w    = (const float*)d_in[3];
  const float* convx_b    = (const float*)d_in[4];
  const float* convfx_w   = (const float*)d_in[5];
  const float* convfx_b   = (const float*)d_in[6];
  const float* slice_w    = (const float*)d_in[7];
  const float* slice_b    = (const float*)d_in[8];
  const float* temperature= (const float*)d_in[9];
  const float* wq         = (const float*)d_in[10];
  const float* wk         = (const float*)d_in[11];
  const float* wv         = (const float*)d_in[12];
  const float* wo         = (const float*)d_in[13];
  const float* bo         = (const float*)d_in[14];
  const float* ln2_w      = (const float*)d_in[15];
  const float* ln2_b      = (const float*)d_in[16];
  const float* w1         = (const float*)d_in[17];
  const float* b1         = (const float*)d_in[18];
  const float* w2         = (const float*)d_in[19];
  const float* b2         = (const float*)d_in[20];
  const float* ln3_w      = (const float*)d_in[21];
  const float* ln3_b      = (const float*)d_in[22];
  const float* w_out      = (const float*)d_in[23];
  const float* b_out      = (const float*)d_in[24];
  float* out = (float*)d_out;

  char* ws = (char*)d_ws;
  size_t off = 0;
  auto alloc = [&](size_t bytes) -> void* {
    void* p = ws + off;
    off += (bytes + 255) & ~(size_t)255;
    return p;
  };
  float* fx32  = (float*)alloc((size_t)BB * NN * CC * 4);    // 64 MiB
  bf16* xln    = (bf16*)alloc((size_t)BB * NN * CC * 2);     // 32 MiB
  char* uni    = (char*)alloc((size_t)BB * NN * 512 * 2 * 2);// xmid/fxmid/swb region
  bf16* xmid   = (bf16*)uni;
  bf16* fxmid  = (bf16*)(uni + (size_t)BB * NN * INNERC * 2);
  bf16* swb    = (bf16*)(uni + (size_t)2 * BB * NN * INNERC * 2);
  float* stp   = (float*)uni;                                // 8 MiB (aliases dead xmid)
  float* normp = (float*)(uni + (size_t)SPLIT * BB * NHEADS * GG * DHD * 4);
  bf16* wtx    = (bf16*)alloc((size_t)LL * 9 * CC * INNERC * 2);
  bf16* wtfx   = (bf16*)alloc((size_t)LL * 9 * CC * INNERC * 2);
  bf16* w1t    = (bf16*)alloc((size_t)LL * CC * HIDD * 2);
  bf16* w2t    = (bf16*)alloc((size_t)LL * HIDD * CC * 2);
  float* otb   = (float*)alloc((size_t)BB * NHEADS * GG * DHD * 4);
  bf16* wct    = (bf16*)alloc((size_t)BB * CC * NHEADS * GG * 2);   // 1 MiB
  (void)ws_size; (void)in_sizes; (void)n_in; (void)out_size;

  transpose_cast_kernel<<<dim3(8, 8, LL * 9), 256, 0, stream>>>(convx_w, wtx, CC, INNERC);
  transpose_cast_kernel<<<dim3(8, 8, LL * 9), 256, 0, stream>>>(convfx_w, wtfx, CC, INNERC);
  transpose_cast_kernel<<<dim3(32, 8, LL), 256, 0, stream>>>(w1, w1t, CC, HIDD);
  transpose_cast_kernel<<<dim3(8, 32, LL), 256, 0, stream>>>(w2, w2t, HIDD, CC);

  hipMemcpyAsync(fx32, fx_in, (size_t)BB * NN * CC * sizeof(float),
                 hipMemcpyDeviceToDevice, stream);

  const int M = BB * NN;  // 65536
  for (int i = 0; i < LL; ++i) {
    ln_kernel<<<M, 256, 0, stream>>>(fx32, ln1_w + i * CC, ln1_b + i * CC, xln);
    conv_mfma_kernel<<<BB * HH * 2, 256, 0, stream>>>(
        xln, wtfx + (size_t)i * 9 * CC * INNERC, convfx_b + i * INNERC, fxmid);
    conv_mfma_kernel<<<BB * HH * 2, 256, 0, stream>>>(
        xln, wtx + (size_t)i * 9 * CC * INNERC, convx_b + i * INNERC, xmid);
    slice_softmax_kernel<<<M / SSP, 256, 0, stream>>>(
        xmid, slice_w + i * DHD * GG, slice_b + i * GG, temperature + i * NHEADS, swb);
    slice_st_kernel<<<dim3(SPLIT, NHEADS, BB), 256, 0, stream>>>(fxmid, swb, stp, normp);
    attn_kernel<<<BB * NHEADS, 256, 0, stream>>>(
        stp, normp, wq + i * DHD * DHD, wk + i * DHD * DHD, wv + i * DHD * DHD, otb);
    wc_kernel<<<BB * NHEADS, 256, 0, stream>>>(otb, wo + (size_t)i * INNERC * CC, wct);
    // fx[b] += sw[b] @ Wc[b] + bo   (deslice + wo-projection fused)
    gemm_acc_kernel<<<dim3(NN / 128, CC / 128, BB), 256, 0, stream>>>(
        swb, wct, bo + i * CC, fx32, NN, CC, NHEADS * GG,
        (size_t)NN * (NHEADS * GG), (size_t)CC * (NHEADS * GG), (size_t)NN * CC);
    ln_kernel<<<M, 256, 0, stream>>>(fx32, ln2_w + i * CC, ln2_b + i * CC, xln);
    mlp_fused_kernel<<<M / 128, 1024, 0, stream>>>(
        xln, w1t + (size_t)i * CC * HIDD, b1 + i * HIDD,
        w2t + (size_t)i * HIDD * CC, b2 + i * CC, fx32);
  }
  head_kernel<<<M, 256, 0, stream>>>(fx32, ln3_w, ln3_b, w_out, b_out, out);
}

// Round 11
// 2997.208 us; speedup vs baseline: 1.1383x; 1.1383x over previous
//
#include <hip/hip_runtime.h>
#include <hip/hip_bf16.h>

typedef __hip_bfloat16 bf16;
typedef __bf16 bfv8 __attribute__((ext_vector_type(8)));
typedef float f32x4 __attribute__((ext_vector_type(4)));

#define BB 4
#define HH 128
#define WWI 128
#define NN 16384      // HH*WWI
#define CC 256
#define LL 4
#define NHEADS 8
#define DHD 32
#define GG 64
#define INNERC 256    // NHEADS*DHD
#define HIDD 1024
#define SPLIT 32      // split-K blocks per (b,h) in slice_st
#define SSP 16        // points per block in slice_softmax

__device__ __forceinline__ float b2f(bf16 x) { return __bfloat162float(x); }
__device__ __forceinline__ bf16 f2b(float x) { return __float2bfloat16(x); }
__device__ __forceinline__ float us2f(unsigned short v) {
  return __uint_as_float(((unsigned)v) << 16);
}

// async global->LDS, 16B per lane; LDS dest = wave-uniform base + lane*16
__device__ __forceinline__ void async16(void* l, const void* g) {
  __builtin_amdgcn_global_load_lds(
      (const __attribute__((address_space(1))) void*)g,
      (__attribute__((address_space(3))) void*)l, 16, 0, 0);
}

__device__ __forceinline__ float wave_sum(float v) {
#pragma unroll
  for (int off = 32; off > 0; off >>= 1) v += __shfl_down(v, off, 64);
  return v;
}

__device__ __forceinline__ float gelu_exact(float x) {
  return 0.5f * x * (1.0f + erff(x * 0.70710678118654752f));
}

// ---------- batched transpose+cast: src fp32 [T][R][Cm] -> dst bf16 [T][Cm][R] ----------
__global__ void transpose_cast_kernel(const float* __restrict__ src, bf16* __restrict__ dst,
                                      int R, int Cm) {
  __shared__ float tile[32][33];
  int tb = blockIdx.z;
  const float* s = src + (size_t)tb * R * Cm;
  bf16* d = dst + (size_t)tb * R * Cm;
  int c0 = blockIdx.x * 32, r0 = blockIdx.y * 32;
  int tx = threadIdx.x & 31, ty = threadIdx.x >> 5;  // 32 x 8
  for (int rr = ty; rr < 32; rr += 8) {
    int r = r0 + rr, c = c0 + tx;
    tile[rr][tx] = (r < R && c < Cm) ? s[(size_t)r * Cm + c] : 0.f;
  }
  __syncthreads();
  for (int cc = ty; cc < 32; cc += 8) {
    int c = c0 + cc, r = r0 + tx;
    if (c < Cm && r < R) d[(size_t)c * R + r] = f2b(tile[tx][cc]);
  }
}

// ---------- LayerNorm over C=256 per point; block = 256 threads ----------
__global__ void ln_kernel(const float* __restrict__ x, const float* __restrict__ w,
                          const float* __restrict__ b, bf16* __restrict__ out) {
  int pp = blockIdx.x;
  int t = threadIdx.x;
  float v = x[(size_t)pp * CC + t];
  float s = wave_sum(v);
  float sq = wave_sum(v * v);
  __shared__ float ls[4], lq[4];
  int wid = t >> 6, lane = t & 63;
  if (lane == 0) { ls[wid] = s; lq[wid] = sq; }
  __syncthreads();
  float tot = ls[0] + ls[1] + ls[2] + ls[3];
  float totq = lq[0] + lq[1] + lq[2] + lq[3];
  float mean = tot * (1.0f / CC);
  float var = totq * (1.0f / CC) - mean * mean;
  float rstd = rsqrtf(var + 1e-5f);
  float o = (v - mean) * rstd * w[t] + b[t];
  out[(size_t)pp * CC + t] = f2b(o);
}

// ---------- 3x3 conv as implicit MFMA GEMM (round-7 proven: B staged via LDS) ----------
__global__ __launch_bounds__(256, 2) void conv_mfma_kernel(
    const bf16* __restrict__ xln, const bf16* __restrict__ wt,
    const float* __restrict__ bias, bf16* __restrict__ out) {
  __shared__ __align__(16) unsigned short As[3 * 130 * 64];
  __shared__ __align__(16) unsigned short Bsm[128 * 64];
  int bid = blockIdx.x;
  int nh = bid & 1;
  int h = (bid >> 1) & 127;
  int b = bid >> 8;
  int t = threadIdx.x, lane = t & 63, wid = t >> 6;
  int wm = (wid >> 1) * 64, wn = (wid & 1) * 64;
  int l15 = lane & 15, l4 = lane >> 4;
  f32x4 acc[4][4];
#pragma unroll
  for (int mi = 0; mi < 4; ++mi)
#pragma unroll
    for (int ni = 0; ni < 4; ++ni) acc[mi][ni] = (f32x4){0.f, 0.f, 0.f, 0.f};
  const bf16* xbase = xln + (size_t)b * NN * CC;

  for (int q = 0; q < 4; ++q) {
    __syncthreads();
    for (int u = t; u < 3120; u += 256) {
      int jp = u & 7;
      int pc = u >> 3;
      int r = pc / 130, cl = pc - r * 130;
      int j = jp ^ (cl & 7);
      int gr = h + r - 1, gc = cl - 1;
      uint4 v = make_uint4(0u, 0u, 0u, 0u);
      if ((unsigned)gr < 128u && (unsigned)gc < 128u)
        v = *(const uint4*)(xbase + ((size_t)(gr * WWI + gc)) * CC + q * 64 + j * 8);
      *(uint4*)(&As[(size_t)u * 8]) = v;
    }
    for (int tap = 0; tap < 9; ++tap) {
      if (tap > 0) __syncthreads();
      {
        const bf16* wsrc = wt + ((size_t)tap * 256 + nh * 128) * 256 + q * 64;
#pragma unroll
        for (int i = 0; i < 4; ++i) {
          int u = t + (i << 8);
          int n = u >> 3, jp = u & 7, j = jp ^ (n & 7);
          uint4 v = *(const uint4*)(wsrc + (size_t)n * 256 + j * 8);
          *(uint4*)(&Bsm[(size_t)u * 8]) = v;
        }
      }
      __syncthreads();
      int ky = tap / 3, kx = tap - ky * 3;
#pragma unroll
      for (int s = 0; s < 2; ++s) {
        bfv8 af[4], bfr[4];
#pragma unroll
        for (int mi = 0; mi < 4; ++mi) {
          int cl = wm + mi * 16 + l15 + kx;
          af[mi] = *(const bfv8*)(&As[((size_t)(ky * 130 + cl)) * 64 +
                                      (((s * 4 + l4) ^ (cl & 7)) << 3)]);
        }
#pragma unroll
        for (int ni = 0; ni < 4; ++ni) {
          int rn = wn + ni * 16 + l15;
          bfr[ni] = *(const bfv8*)(&Bsm[(size_t)rn * 64 + (((s * 4 + l4) ^ (rn & 7)) << 3)]);
        }
#pragma unroll
        for (int mi = 0; mi < 4; ++mi)
#pragma unroll
          for (int ni = 0; ni < 4; ++ni)
            acc[mi][ni] = __builtin_amdgcn_mfma_f32_16x16x32_bf16(af[mi], bfr[ni], acc[mi][ni], 0, 0, 0);
      }
    }
  }
  int colB = wn + l15;
  int rowB = wm + l4 * 4;
#pragma unroll
  for (int ni = 0; ni < 4; ++ni) {
    int oc = nh * 128 + colB + ni * 16;
    float bv = bias[oc];
#pragma unroll
    for (int mi = 0; mi < 4; ++mi) {
#pragma unroll
      for (int r = 0; r < 4; ++r) {
        int pix = rowB + mi * 16 + r;
        out[((size_t)(b * NN + h * WWI + pix)) * CC + oc] = f2b(acc[mi][ni][r] + bv);
      }
    }
  }
}

// ---------- z-batched MFMA GEMM, outf += acc + bias; async global_load_lds staging ----------
// LDS layout per tile: [row-group g 0..7][kgrp 0..7][row-in-group 0..15][8 bf16]
// staging instruction (g,h): lane = (h*4+q4-half)*... lane k-half maps to lane*16B exactly.
__global__ __launch_bounds__(256, 2) void gemm_acc_kernel(
    const bf16* __restrict__ A, const bf16* __restrict__ BT,
    const float* __restrict__ bias, float* __restrict__ outf,
    int M, int N, int K, size_t strideAz, size_t strideBz, size_t strideOz) {
  A  += (size_t)blockIdx.z * strideAz;
  BT += (size_t)blockIdx.z * strideBz;
  __shared__ __align__(16) unsigned short As[128 * 64];   // 16 KiB
  __shared__ __align__(16) unsigned short Bs[128 * 64];   // 16 KiB
  int m0 = blockIdx.x * 128, n0 = blockIdx.y * 128;
  int t = threadIdx.x, lane = t & 63, wid = t >> 6;
  int wm = (wid >> 1) * 64, wn = (wid & 1) * 64;
  int l15 = lane & 15, q4 = lane >> 4;
  int wg = wm >> 4, ng = wn >> 4;
  f32x4 acc[4][4];
#pragma unroll
  for (int mi = 0; mi < 4; ++mi)
#pragma unroll
    for (int ni = 0; ni < 4; ++ni) acc[mi][ni] = (f32x4){0.f, 0.f, 0.f, 0.f};

  for (int kb = 0; kb < K; kb += 64) {
    __syncthreads();                      // previous compute done; LDS free
#pragma unroll
    for (int i = 0; i < 4; ++i) {
      int inst = wid * 4 + i;             // 0..15
      int g = inst >> 1, h2 = inst & 1;
      int row = g * 16 + l15;
      int kc = (h2 * 4 + q4) * 8;
      async16(&As[(size_t)g * 1024 + h2 * 512], A + (size_t)(m0 + row) * K + kb + kc);
      async16(&Bs[(size_t)g * 1024 + h2 * 512], BT + (size_t)(n0 + row) * K + kb + kc);
    }
    __syncthreads();                      // drains vmcnt (global_load_lds) + barrier
#pragma unroll
    for (int s = 0; s < 2; ++s) {
      int kgrp = s * 4 + q4;
      bfv8 af[4], bfr[4];
#pragma unroll
      for (int mi = 0; mi < 4; ++mi)
        af[mi] = *(const bfv8*)(&As[(size_t)(wg + mi) * 1024 + kgrp * 128 + l15 * 8]);
#pragma unroll
      for (int ni = 0; ni < 4; ++ni)
        bfr[ni] = *(const bfv8*)(&Bs[(size_t)(ng + ni) * 1024 + kgrp * 128 + l15 * 8]);
#pragma unroll
      for (int mi = 0; mi < 4; ++mi)
#pragma unroll
        for (int ni = 0; ni < 4; ++ni)
          acc[mi][ni] = __builtin_amdgcn_mfma_f32_16x16x32_bf16(af[mi], bfr[ni], acc[mi][ni], 0, 0, 0);
    }
  }
  int colB = n0 + wn + l15;
  int rowB = m0 + wm + q4 * 4;
#pragma unroll
  for (int ni = 0; ni < 4; ++ni) {
    int col = colB + ni * 16;
    float bv = bias[col];
#pragma unroll
    for (int mi = 0; mi < 4; ++mi) {
#pragma unroll
      for (int r = 0; r < 4; ++r) {
        int row = rowB + mi * 16 + r;
        outf[(size_t)blockIdx.z * strideOz + (size_t)row * N + col] += acc[mi][ni][r] + bv;
      }
    }
  }
}

// ---------- fused MLP (round-7 proven): all MFMA operands from LDS ----------
// block = 512 threads (8 waves), 128 rows x full C=256 out per block.
__global__ __launch_bounds__(512, 2) void mlp_fused_kernel(
    const bf16* __restrict__ xln, const bf16* __restrict__ w1t,
    const float* __restrict__ b1, const bf16* __restrict__ w2t,
    const float* __restrict__ b2, float* __restrict__ fx) {
  __shared__ __align__(16) unsigned short As[128 * 256];  // 64 KiB, xln tile (per-64 XOR swizzle)
  __shared__ __align__(16) bf16 Hs[128 * 128];            // 32 KiB, one hidden chunk
  __shared__ __align__(16) unsigned short Wb[256 * 64];   // 32 KiB, weight staging
  int m0 = blockIdx.x * 128;
  int t = threadIdx.x, lane = t & 63, wid = t >> 6;
  int l15 = lane & 15, q4 = lane >> 4;
  int wm2 = (wid & 1) * 64, wn2 = (wid >> 1) * 32;
  int wm = (wid & 1) * 64, wn = (wid >> 1) * 64;

  const unsigned short* xg = (const unsigned short*)xln + (size_t)m0 * 256;
#pragma unroll
  for (int i = 0; i < 8; ++i) {
    int u = t + i * 512;
    int row = u >> 5, v = u & 31;
    int kb = v >> 3, jp = v & 7;
    uint4 val = ((const uint4*)xg)[u];
    ((uint4*)As)[row * 32 + kb * 8 + (jp ^ (row & 7))] = val;
  }

  f32x4 accO[4][4];
#pragma unroll
  for (int mi = 0; mi < 4; ++mi)
#pragma unroll
    for (int ni = 0; ni < 4; ++ni) accO[mi][ni] = (f32x4){0.f, 0.f, 0.f, 0.f};

  for (int j = 0; j < 8; ++j) {
    int hbase = j * 128;
    f32x4 acc2[4][2];
#pragma unroll
    for (int mi = 0; mi < 4; ++mi)
#pragma unroll
      for (int nj = 0; nj < 2; ++nj) acc2[mi][nj] = (f32x4){0.f, 0.f, 0.f, 0.f};
    for (int kb = 0; kb < 4; ++kb) {
      __syncthreads();
#pragma unroll
      for (int i = 0; i < 2; ++i) {
        int u = t + i * 512;
        int n = u >> 3, jp = u & 7;
        uint4 val = *(const uint4*)(w1t + (size_t)(hbase + n) * 256 + kb * 64 + jp * 8);
        ((uint4*)Wb)[n * 8 + (jp ^ (n & 7))] = val;
      }
      __syncthreads();
#pragma unroll
      for (int ks = 0; ks < 2; ++ks) {
        int kgrp = ks * 4 + q4;
        bfv8 af[4], bfr[2];
#pragma unroll
        for (int mi = 0; mi < 4; ++mi) {
          int row = wm2 + mi * 16 + l15;
          af[mi] = *(const bfv8*)(&As[row * 256 + kb * 64 + ((kgrp ^ (row & 7)) << 3)]);
        }
#pragma unroll
        for (int nj = 0; nj < 2; ++nj) {
          int n = wn2 + nj * 16 + l15;
          bfr[nj] = *(const bfv8*)(&Wb[n * 64 + ((kgrp ^ (n & 7)) << 3)]);
        }
#pragma unroll
        for (int mi = 0; mi < 4; ++mi)
#pragma unroll
          for (int nj = 0; nj < 2; ++nj)
            acc2[mi][nj] = __builtin_amdgcn_mfma_f32_16x16x32_bf16(af[mi], bfr[nj], acc2[mi][nj], 0, 0, 0);
      }
    }
#pragma unroll
    for (int nj = 0; nj < 2; ++nj) {
      int coln = wn2 + nj * 16 + l15;
      float bv = b1[hbase + coln];
      int half = coln >> 6, sub = (coln >> 3) & 7, lo = coln & 7;
#pragma unroll
      for (int mi = 0; mi < 4; ++mi) {
#pragma unroll
        for (int r = 0; r < 4; ++r) {
          int row = wm2 + mi * 16 + q4 * 4 + r;
          float v = acc2[mi][nj][r] + bv;
          Hs[row * 128 + half * 64 + (((sub ^ (row & 7)) << 3) + lo)] = f2b(gelu_exact(v));
        }
      }
    }
    for (int kb2 = 0; kb2 < 2; ++kb2) {
      __syncthreads();
#pragma unroll
      for (int i = 0; i < 4; ++i) {
        int u = t + i * 512;
        int n = u >> 3, jp = u & 7;
        uint4 val = *(const uint4*)(w2t + (size_t)n * 1024 + hbase + kb2 * 64 + jp * 8);
        ((uint4*)Wb)[n * 8 + (jp ^ (n & 7))] = val;
      }
      __syncthreads();
#pragma unroll
      for (int ks = 0; ks < 2; ++ks) {
        int kgrp = ks * 4 + q4;
        bfv8 af[4], bfr[4];
#pragma unroll
        for (int mi = 0; mi < 4; ++mi) {
          int row = wm + mi * 16 + l15;
          af[mi] = *(const bfv8*)(&Hs[row * 128 + kb2 * 64 + ((kgrp ^ (row & 7)) << 3)]);
        }
#pragma unroll
        for (int ni = 0; ni < 4; ++ni) {
          int n = wn + ni * 16 + l15;
          bfr[ni] = *(const bfv8*)(&Wb[n * 64 + ((kgrp ^ (n & 7)) << 3)]);
        }
#pragma unroll
        for (int mi = 0; mi < 4; ++mi)
#pragma unroll
          for (int ni = 0; ni < 4; ++ni)
            accO[mi][ni] = __builtin_amdgcn_mfma_f32_16x16x32_bf16(af[mi], bfr[ni], accO[mi][ni], 0, 0, 0);
      }
    }
  }
#pragma unroll
  for (int ni = 0; ni < 4; ++ni) {
    int col = wn + ni * 16 + l15;
    float bv = b2[col];
#pragma unroll
    for (int mi = 0; mi < 4; ++mi) {
#pragma unroll
      for (int r = 0; r < 4; ++r) {
        int row = m0 + wm + mi * 16 + q4 * 4 + r;
        fx[(size_t)row * 256 + col] += accO[mi][ni][r] + bv;
      }
    }
  }
}

// ---------- slice logits + softmax over G; 16 points/block, weights in LDS ----------
__global__ __launch_bounds__(256) void slice_softmax_kernel(
    const bf16* __restrict__ xmid, const float* __restrict__ sw_w,
    const float* __restrict__ sw_b, const float* __restrict__ temp,
    bf16* __restrict__ swout) {
  __shared__ float wsm[32][64];     // 8 KiB  [d][g]
  __shared__ float xm[SSP][256];    // 16 KiB
  __shared__ float bias_s[64];
  __shared__ float rtc[8];
  int p0 = blockIdx.x * SSP;
  int t = threadIdx.x;
  for (int i = t; i < 2048; i += 256) wsm[i >> 6][i & 63] = sw_w[i];
  if (t < 64) bias_s[t] = sw_b[t];
  if (t < 8) {
    float x = temp[t];
    rtc[t] = 1.0f / fminf(fmaxf(x, 0.1f), 5.0f);
  }
  const unsigned short* xg = (const unsigned short*)xmid + (size_t)p0 * 256;
#pragma unroll
  for (int i2 = t; i2 < SSP * 32; i2 += 256) {
    uint4 v = ((const uint4*)xg)[i2];
    int p = i2 >> 5, c = (i2 & 31) << 3;
    xm[p][c + 0] = us2f((unsigned short)(v.x & 0xffff));
    xm[p][c + 1] = us2f((unsigned short)(v.x >> 16));
    xm[p][c + 2] = us2f((unsigned short)(v.y & 0xffff));
    xm[p][c + 3] = us2f((unsigned short)(v.y >> 16));
    xm[p][c + 4] = us2f((unsigned short)(v.z & 0xffff));
    xm[p][c + 5] = us2f((unsigned short)(v.z >> 16));
    xm[p][c + 6] = us2f((unsigned short)(v.w & 0xffff));
    xm[p][c + 7] = us2f((unsigned short)(v.w >> 16));
  }
  __syncthreads();
  int g = t & 63, pq = t >> 6;
  for (int pp2 = 0; pp2 < SSP / 4; ++pp2) {
    int p = pp2 * 4 + pq;
#pragma unroll
    for (int h = 0; h < NHEADS; ++h) {
      float acc = bias_s[g];
      const float* xr = &xm[p][h * 32];
#pragma unroll
      for (int d = 0; d < 32; ++d) acc += xr[d] * wsm[d][g];
      float logit = acc * rtc[h];
      float m = logit;
#pragma unroll
      for (int off = 32; off > 0; off >>= 1) m = fmaxf(m, __shfl_xor(m, off, 64));
      float e = __expf(logit - m);
      float s = e;
#pragma unroll
      for (int off = 32; off > 0; off >>= 1) s += __shfl_xor(s, off, 64);
      swout[(size_t)(p0 + p) * 512 + h * 64 + g] = f2b(e / s);
    }
  }
}

// ---------- slice reduce as split-K MFMA outer product ----------
__global__ __launch_bounds__(256) void slice_st_kernel(
    const bf16* __restrict__ fxmid, const bf16* __restrict__ sw,
    float* __restrict__ stp, float* __restrict__ normp) {
  __shared__ __align__(16) unsigned short sw_s[64 * 64];
  __shared__ __align__(16) unsigned short fx_s[32 * 64];
  __shared__ float npart[2][64];
  int split = blockIdx.x, h = blockIdx.y, b = blockIdx.z;
  int t = threadIdx.x, w = t >> 6, lane = t & 63;
  int l15 = lane & 15, q4 = lane >> 4;
  int ns0 = split * (NN / SPLIT);
  const int NT = (NN / SPLIT) / 64;
  f32x4 acc0 = {0.f, 0.f, 0.f, 0.f}, acc1 = {0.f, 0.f, 0.f, 0.f};
  float nacc = 0.f;
  const unsigned short* swg = (const unsigned short*)sw + (size_t)b * NN * 512 + h * 64;
  const unsigned short* fxg = (const unsigned short*)fxmid + (size_t)b * NN * 256 + h * 32;

  for (int kt = 0; kt < NT; ++kt) {
    int n0 = ns0 + kt * 64;
    __syncthreads();
    if (w < 2) {
      int g = lane;
#pragma unroll
      for (int i = 0; i < 4; ++i) {
        int j = w + 2 * i;
        const unsigned short* p = swg + (size_t)(n0 + j * 8) * 512 + g;
        unsigned short v0 = p[0],     v1 = p[512],  v2 = p[1024], v3 = p[1536];
        unsigned short v4 = p[2048],  v5 = p[2560], v6 = p[3072], v7 = p[3584];
        nacc += us2f(v0) + us2f(v1) + us2f(v2) + us2f(v3) +
                us2f(v4) + us2f(v5) + us2f(v6) + us2f(v7);
        uint4 pk = make_uint4((unsigned)v0 | ((unsigned)v1 << 16),
                              (unsigned)v2 | ((unsigned)v3 << 16),
                              (unsigned)v4 | ((unsigned)v5 << 16),
                              (unsigned)v6 | ((unsigned)v7 << 16));
        ((uint4*)sw_s)[g * 8 + (j ^ (g & 7))] = pk;
      }
    } else {
      int d = lane & 31, nh = lane >> 5, w3 = w - 2;
#pragma unroll
      for (int i = 0; i < 2; ++i) {
        int nbase = (w3 * 2 + i) * 16 + nh * 8;
        const unsigned short* p = fxg + (size_t)(n0 + nbase) * 256 + d;
        unsigned short v0 = p[0],    v1 = p[256],  v2 = p[512],  v3 = p[768];
        unsigned short v4 = p[1024], v5 = p[1280], v6 = p[1536], v7 = p[1792];
        uint4 pk = make_uint4((unsigned)v0 | ((unsigned)v1 << 16),
                              (unsigned)v2 | ((unsigned)v3 << 16),
                              (unsigned)v4 | ((unsigned)v5 << 16),
                              (unsigned)v6 | ((unsigned)v7 << 16));
        int u = nbase >> 3;
        ((uint4*)fx_s)[d * 8 + (u ^ (d & 7))] = pk;
      }
    }
    __syncthreads();
    int gg = w * 16 + l15;
    int d0 = l15, d1 = 16 + l15;
#pragma unroll
    for (int ks = 0; ks < 2; ++ks) {
      bfv8 af  = ((const bfv8*)sw_s)[gg * 8 + ((ks * 4 + q4) ^ (gg & 7))];
      bfv8 bf0 = ((const bfv8*)fx_s)[d0 * 8 + ((ks * 4 + q4) ^ (d0 & 7))];
      bfv8 bf1 = ((const bfv8*)fx_s)[d1 * 8 + ((ks * 4 + q4) ^ (d1 & 7))];
      acc0 = __builtin_amdgcn_mfma_f32_16x16x32_bf16(af, bf0, acc0, 0, 0, 0);
      acc1 = __builtin_amdgcn_mfma_f32_16x16x32_bf16(af, bf1, acc1, 0, 0, 0);
    }
  }
  if (w < 2) npart[w][lane] = nacc;
  __syncthreads();
  int bh = b * NHEADS + h;
  if (t < 64) normp[(size_t)split * (BB * NHEADS * GG) + bh * 64 + t] = npart[0][t] + npart[1][t];
  size_t base = ((size_t)split * (BB * NHEADS * GG) + bh * 64) * 32;
#pragma unroll
  for (int r = 0; r < 4; ++r) {
    int g = w * 16 + q4 * 4 + r;
    stp[base + (size_t)g * 32 + l15] = acc0[r];
    stp[base + (size_t)g * 32 + 16 + l15] = acc1[r];
  }
}

// ---------- attention over G=64 per (b,h); 256 threads; weights + reduction in LDS ----------
__global__ __launch_bounds__(256) void attn_kernel(
    const float* __restrict__ stp, const float* __restrict__ normp,
    const float* __restrict__ wq, const float* __restrict__ wk,
    const float* __restrict__ wv, float* __restrict__ ot) {
  __shared__ float wqs[32 * 32], wks[32 * 32], wvs[32 * 32];
  __shared__ float st[GG][DHD + 1];
  __shared__ float qq[GG][DHD + 1], kk[GG][DHD + 1], vv[GG][DHD + 1];
  __shared__ float pm[GG][GG + 1];
  __shared__ float nrm[GG];
  int bh = blockIdx.x;
  int t = threadIdx.x;
  ((float4*)wqs)[t] = ((const float4*)wq)[t];
  ((float4*)wks)[t] = ((const float4*)wk)[t];
  ((float4*)wvs)[t] = ((const float4*)wv)[t];
  if (t < 64) {
    float ns = 0.f;
    for (int s = 0; s < SPLIT; ++s) ns += normp[(size_t)s * (BB * NHEADS * GG) + bh * 64 + t];
    nrm[t] = 1.0f / (ns + 1e-5f);
  }
  __syncthreads();
#pragma unroll
  for (int i = 0; i < 8; ++i) {
    int idx = t + i * 256;
    int g = idx >> 5, d = idx & 31;
    float a = 0.f;
    for (int s = 0; s < SPLIT; ++s)
      a += stp[((size_t)s * (BB * NHEADS * GG) + bh * 64 + g) * 32 + d];
    st[g][d] = a * nrm[g];
  }
  __syncthreads();
#pragma unroll
  for (int i = 0; i < 8; ++i) {
    int idx = t + i * 256;
    int g = idx >> 5, d = idx & 31;
    float aq = 0.f, ak = 0.f, av = 0.f;
#pragma unroll
    for (int c = 0; c < 32; ++c) {
      float sv = st[g][c];
      aq += sv * wqs[c * 32 + d];
      ak += sv * wks[c * 32 + d];
      av += sv * wvs[c * 32 + d];
    }
    qq[g][d] = aq; kk[g][d] = ak; vv[g][d] = av;
  }
  __syncthreads();
  {
    int g = t >> 2, sub = t & 3;
    float sc[16];
    float m = -1e30f;
    const float scale = 0.17677669529663687f;
#pragma unroll
    for (int jj = 0; jj < 16; ++jj) {
      int j = sub * 16 + jj;
      float a = 0.f;
#pragma unroll
      for (int d = 0; d < 32; ++d) a += qq[g][d] * kk[j][d];
      a *= scale;
      sc[jj] = a;
      m = fmaxf(m, a);
    }
    m = fmaxf(m, __shfl_xor(m, 1, 64));
    m = fmaxf(m, __shfl_xor(m, 2, 64));
    float ssum = 0.f;
#pragma unroll
    for (int jj = 0; jj < 16; ++jj) { sc[jj] = __expf(sc[jj] - m); ssum += sc[jj]; }
    ssum += __shfl_xor(ssum, 1, 64);
    ssum += __shfl_xor(ssum, 2, 64);
    float rs = 1.0f / ssum;
#pragma unroll
    for (int jj = 0; jj < 16; ++jj) pm[g][sub * 16 + jj] = sc[jj] * rs;
  }
  __syncthreads();
#pragma unroll
  for (int i = 0; i < 8; ++i) {
    int idx = t + i * 256;
    int g = idx >> 5, d = idx & 31;
    float a = 0.f;
#pragma unroll
    for (int j = 0; j < GG; ++j) a += pm[g][j] * vv[j][d];
    ot[((size_t)bh * GG + g) * DHD + d] = a;
  }
}

// ---------- Wc^T[b][c][h*64+g] = sum_d ot[b,h,g,d] * wo[h*32+d, c]  (bf16 out) ----------
__global__ __launch_bounds__(256) void wc_kernel(const float* __restrict__ ot,
                                                 const float* __restrict__ wo,
                                                 bf16* __restrict__ wct) {
  __shared__ float ots[GG][DHD];   // 8 KiB
  int bh = blockIdx.x;             // b*8 + h
  int h = bh & 7, b = bh >> 3;
  int t = threadIdx.x;             // 256 = c
  for (int i = t; i < GG * DHD; i += 256) ots[i >> 5][i & 31] = ot[(size_t)bh * (GG * DHD) + i];
  float wol[DHD];
#pragma unroll
  for (int d = 0; d < DHD; ++d) wol[d] = wo[(size_t)(h * DHD + d) * CC + t];
  __syncthreads();
  bf16* dst = wct + ((size_t)b * CC + t) * (NHEADS * GG) + h * GG;
#pragma unroll 4
  for (int g = 0; g < GG; ++g) {
    float a = 0.f;
#pragma unroll
    for (int d = 0; d < DHD; ++d) a += wol[d] * ots[g][d];
    dst[g] = f2b(a);
  }
}

// ---------- final LN3 + head (C -> 4) ----------
__global__ void head_kernel(const float* __restrict__ fx, const float* __restrict__ w,
                            const float* __restrict__ b, const float* __restrict__ wout,
                            const float* __restrict__ bout, float* __restrict__ out) {
  int pp = blockIdx.x;
  int t = threadIdx.x;
  float v = fx[(size_t)pp * CC + t];
  float s = wave_sum(v);
  float sq = wave_sum(v * v);
  __shared__ float ls[4], lq[4];
  int wid = t >> 6, lane = t & 63;
  if (lane == 0) { ls[wid] = s; lq[wid] = sq; }
  __syncthreads();
  float tot = ls[0] + ls[1] + ls[2] + ls[3];
  float totq = lq[0] + lq[1] + lq[2] + lq[3];
  float mean = tot * (1.0f / CC);
  float var = totq * (1.0f / CC) - mean * mean;
  float rstd = rsqrtf(var + 1e-5f);
  float xn = (v - mean) * rstd * w[t] + b[t];
  __shared__ float xs[CC];
  xs[t] = xn;
  __syncthreads();
  if (t < 4) {
    float a = bout[t];
    for (int c = 0; c < CC; ++c) a += xs[c] * wout[c * 4 + t];
    out[(size_t)pp * 4 + t] = a;
  }
}

extern "C" void kernel_launch(void* const* d_in, const int* in_sizes, int n_in,
                              void* d_out, int out_size, void* d_ws, size_t ws_size,
                              hipStream_t stream) {
  const float* fx_in      = (const float*)d_in[0];
  const float* ln1_w      = (const float*)d_in[1];
  const float* ln1_b      = (const float*)d_in[2];
  const float* convx_w    = (const float*)d_in[3];
  const float* convx_b    = (const float*)d_in[4];
  const float* convfx_w   = (const float*)d_in[5];
  const float* convfx_b   = (const float*)d_in[6];
  const float* slice_w    = (const float*)d_in[7];
  const float* slice_b    = (const float*)d_in[8];
  const float* temperature= (const float*)d_in[9];
  const float* wq         = (const float*)d_in[10];
  const float* wk         = (const float*)d_in[11];
  const float* wv         = (const float*)d_in[12];
  const float* wo         = (const float*)d_in[13];
  const float* bo         = (const float*)d_in[14];
  const float* ln2_w      = (const float*)d_in[15];
  const float* ln2_b      = (const float*)d_in[16];
  const float* w1         = (const float*)d_in[17];
  const float* b1         = (const float*)d_in[18];
  const float* w2         = (const float*)d_in[19];
  const float* b2         = (const float*)d_in[20];
  const float* ln3_w      = (const float*)d_in[21];
  const float* ln3_b      = (const float*)d_in[22];
  const float* w_out      = (const float*)d_in[23];
  const float* b_out      = (const float*)d_in[24];
  float* out = (float*)d_out;

  char* ws = (char*)d_ws;
  size_t off = 0;
  auto alloc = [&](size_t bytes) -> void* {
    void* p = ws + off;
    off += (bytes + 255) & ~(size_t)255;
    return p;
  };
  float* fx32  = (float*)alloc((size_t)BB * NN * CC * 4);    // 64 MiB
  bf16* xln    = (bf16*)alloc((size_t)BB * NN * CC * 2);     // 32 MiB
  char* uni    = (char*)alloc((size_t)BB * NN * 512 * 2 * 2);// xmid/fxmid/swb region
  bf16* xmid   = (bf16*)uni;
  bf16* fxmid  = (bf16*)(uni + (size_t)BB * NN * INNERC * 2);
  bf16* swb    = (bf16*)(uni + (size_t)2 * BB * NN * INNERC * 2);
  float* stp   = (float*)uni;                                // 8 MiB (aliases dead xmid)
  float* normp = (float*)(uni + (size_t)SPLIT * BB * NHEADS * GG * DHD * 4);
  bf16* wtx    = (bf16*)alloc((size_t)LL * 9 * CC * INNERC * 2);
  bf16* wtfx   = (bf16*)alloc((size_t)LL * 9 * CC * INNERC * 2);
  bf16* w1t    = (bf16*)alloc((size_t)LL * CC * HIDD * 2);
  bf16* w2t    = (bf16*)alloc((size_t)LL * HIDD * CC * 2);
  float* otb   = (float*)alloc((size_t)BB * NHEADS * GG * DHD * 4);
  bf16* wct    = (bf16*)alloc((size_t)BB * CC * NHEADS * GG * 2);   // 1 MiB
  (void)ws_size; (void)in_sizes; (void)n_in; (void)out_size;

  transpose_cast_kernel<<<dim3(8, 8, LL * 9), 256, 0, stream>>>(convx_w, wtx, CC, INNERC);
  transpose_cast_kernel<<<dim3(8, 8, LL * 9), 256, 0, stream>>>(convfx_w, wtfx, CC, INNERC);
  transpose_cast_kernel<<<dim3(32, 8, LL), 256, 0, stream>>>(w1, w1t, CC, HIDD);
  transpose_cast_kernel<<<dim3(8, 32, LL), 256, 0, stream>>>(w2, w2t, HIDD, CC);

  hipMemcpyAsync(fx32, fx_in, (size_t)BB * NN * CC * sizeof(float),
                 hipMemcpyDeviceToDevice, stream);

  const int M = BB * NN;  // 65536
  for (int i = 0; i < LL; ++i) {
    ln_kernel<<<M, 256, 0, stream>>>(fx32, ln1_w + i * CC, ln1_b + i * CC, xln);
    conv_mfma_kernel<<<BB * HH * 2, 256, 0, stream>>>(
        xln, wtfx + (size_t)i * 9 * CC * INNERC, convfx_b + i * INNERC, fxmid);
    conv_mfma_kernel<<<BB * HH * 2, 256, 0, stream>>>(
        xln, wtx + (size_t)i * 9 * CC * INNERC, convx_b + i * INNERC, xmid);
    slice_softmax_kernel<<<M / SSP, 256, 0, stream>>>(
        xmid, slice_w + i * DHD * GG, slice_b + i * GG, temperature + i * NHEADS, swb);
    slice_st_kernel<<<dim3(SPLIT, NHEADS, BB), 256, 0, stream>>>(fxmid, swb, stp, normp);
    attn_kernel<<<BB * NHEADS, 256, 0, stream>>>(
        stp, normp, wq + i * DHD * DHD, wk + i * DHD * DHD, wv + i * DHD * DHD, otb);
    wc_kernel<<<BB * NHEADS, 256, 0, stream>>>(otb, wo + (size_t)i * INNERC * CC, wct);
    // fx[b] += sw[b] @ Wc[b] + bo   (deslice + wo-projection fused)
    gemm_acc_kernel<<<dim3(NN / 128, CC / 128, BB), 256, 0, stream>>>(
        swb, wct, bo + i * CC, fx32, NN, CC, NHEADS * GG,
        (size_t)NN * (NHEADS * GG), (size_t)CC * (NHEADS * GG), (size_t)NN * CC);
    ln_kernel<<<M, 256, 0, stream>>>(fx32, ln2_w + i * CC, ln2_b + i * CC, xln);
    mlp_fused_kernel<<<M / 128, 512, 0, stream>>>(
        xln, w1t + (size_t)i * CC * HIDD, b1 + i * HIDD,
        w2t + (size_t)i * HIDD * CC, b2 + i * CC, fx32);
  }
  head_kernel<<<M, 256, 0, stream>>>(fx32, ln3_w, ln3_b, w_out, b_out, out);
}

// Round 12
// 2879.365 us; speedup vs baseline: 1.1849x; 1.0409x over previous
//
#include <hip/hip_runtime.h>
#include <hip/hip_bf16.h>

typedef __hip_bfloat16 bf16;
typedef __bf16 bfv8 __attribute__((ext_vector_type(8)));
typedef float f32x4 __attribute__((ext_vector_type(4)));

#define BB 4
#define HH 128
#define WWI 128
#define NN 16384      // HH*WWI
#define CC 256
#define LL 4
#define NHEADS 8
#define DHD 32
#define GG 64
#define INNERC 256    // NHEADS*DHD
#define HIDD 1024
#define SPLIT 32      // split-K blocks per (b,h) in slice_st
#define SSP 16        // points per block in slice_softmax

__device__ __forceinline__ float b2f(bf16 x) { return __bfloat162float(x); }
__device__ __forceinline__ bf16 f2b(float x) { return __float2bfloat16(x); }
__device__ __forceinline__ float us2f(unsigned short v) {
  return __uint_as_float(((unsigned)v) << 16);
}

// async global->LDS, 16B per lane; LDS dest = wave-uniform base + lane*16
__device__ __forceinline__ void async16(void* l, const void* g) {
  __builtin_amdgcn_global_load_lds(
      (const __attribute__((address_space(1))) void*)g,
      (__attribute__((address_space(3))) void*)l, 16, 0, 0);
}

__device__ __forceinline__ float wave_sum(float v) {
#pragma unroll
  for (int off = 32; off > 0; off >>= 1) v += __shfl_down(v, off, 64);
  return v;
}

__device__ __forceinline__ float gelu_exact(float x) {
  return 0.5f * x * (1.0f + erff(x * 0.70710678118654752f));
}

// ---------- batched transpose+cast: src fp32 [T][R][Cm] -> dst bf16 [T][Cm][R] ----------
__global__ void transpose_cast_kernel(const float* __restrict__ src, bf16* __restrict__ dst,
                                      int R, int Cm) {
  __shared__ float tile[32][33];
  int tb = blockIdx.z;
  const float* s = src + (size_t)tb * R * Cm;
  bf16* d = dst + (size_t)tb * R * Cm;
  int c0 = blockIdx.x * 32, r0 = blockIdx.y * 32;
  int tx = threadIdx.x & 31, ty = threadIdx.x >> 5;  // 32 x 8
  for (int rr = ty; rr < 32; rr += 8) {
    int r = r0 + rr, c = c0 + tx;
    tile[rr][tx] = (r < R && c < Cm) ? s[(size_t)r * Cm + c] : 0.f;
  }
  __syncthreads();
  for (int cc = ty; cc < 32; cc += 8) {
    int c = c0 + cc, r = r0 + tx;
    if (c < Cm && r < R) d[(size_t)c * R + r] = f2b(tile[tx][cc]);
  }
}

// ---------- LayerNorm over C=256 per point; block = 256 threads ----------
__global__ void ln_kernel(const float* __restrict__ x, const float* __restrict__ w,
                          const float* __restrict__ b, bf16* __restrict__ out) {
  int pp = blockIdx.x;
  int t = threadIdx.x;
  float v = x[(size_t)pp * CC + t];
  float s = wave_sum(v);
  float sq = wave_sum(v * v);
  __shared__ float ls[4], lq[4];
  int wid = t >> 6, lane = t & 63;
  if (lane == 0) { ls[wid] = s; lq[wid] = sq; }
  __syncthreads();
  float tot = ls[0] + ls[1] + ls[2] + ls[3];
  float totq = lq[0] + lq[1] + lq[2] + lq[3];
  float mean = tot * (1.0f / CC);
  float var = totq * (1.0f / CC) - mean * mean;
  float rstd = rsqrtf(var + 1e-5f);
  float o = (v - mean) * rstd * w[t] + b[t];
  out[(size_t)pp * CC + t] = f2b(o);
}

// ---------- 3x3 conv as implicit MFMA GEMM (round-7 proven: B staged via LDS) ----------
__global__ __launch_bounds__(256, 2) void conv_mfma_kernel(
    const bf16* __restrict__ xln, const bf16* __restrict__ wt,
    const float* __restrict__ bias, bf16* __restrict__ out) {
  __shared__ __align__(16) unsigned short As[3 * 130 * 64];
  __shared__ __align__(16) unsigned short Bsm[128 * 64];
  int bid = blockIdx.x;
  int nh = bid & 1;
  int h = (bid >> 1) & 127;
  int b = bid >> 8;
  int t = threadIdx.x, lane = t & 63, wid = t >> 6;
  int wm = (wid >> 1) * 64, wn = (wid & 1) * 64;
  int l15 = lane & 15, l4 = lane >> 4;
  f32x4 acc[4][4];
#pragma unroll
  for (int mi = 0; mi < 4; ++mi)
#pragma unroll
    for (int ni = 0; ni < 4; ++ni) acc[mi][ni] = (f32x4){0.f, 0.f, 0.f, 0.f};
  const bf16* xbase = xln + (size_t)b * NN * CC;

  for (int q = 0; q < 4; ++q) {
    __syncthreads();
    for (int u = t; u < 3120; u += 256) {
      int jp = u & 7;
      int pc = u >> 3;
      int r = pc / 130, cl = pc - r * 130;
      int j = jp ^ (cl & 7);
      int gr = h + r - 1, gc = cl - 1;
      uint4 v = make_uint4(0u, 0u, 0u, 0u);
      if ((unsigned)gr < 128u && (unsigned)gc < 128u)
        v = *(const uint4*)(xbase + ((size_t)(gr * WWI + gc)) * CC + q * 64 + j * 8);
      *(uint4*)(&As[(size_t)u * 8]) = v;
    }
    for (int tap = 0; tap < 9; ++tap) {
      if (tap > 0) __syncthreads();
      {
        const bf16* wsrc = wt + ((size_t)tap * 256 + nh * 128) * 256 + q * 64;
#pragma unroll
        for (int i = 0; i < 4; ++i) {
          int u = t + (i << 8);
          int n = u >> 3, jp = u & 7, j = jp ^ (n & 7);
          uint4 v = *(const uint4*)(wsrc + (size_t)n * 256 + j * 8);
          *(uint4*)(&Bsm[(size_t)u * 8]) = v;
        }
      }
      __syncthreads();
      int ky = tap / 3, kx = tap - ky * 3;
#pragma unroll
      for (int s = 0; s < 2; ++s) {
        bfv8 af[4], bfr[4];
#pragma unroll
        for (int mi = 0; mi < 4; ++mi) {
          int cl = wm + mi * 16 + l15 + kx;
          af[mi] = *(const bfv8*)(&As[((size_t)(ky * 130 + cl)) * 64 +
                                      (((s * 4 + l4) ^ (cl & 7)) << 3)]);
        }
#pragma unroll
        for (int ni = 0; ni < 4; ++ni) {
          int rn = wn + ni * 16 + l15;
          bfr[ni] = *(const bfv8*)(&Bsm[(size_t)rn * 64 + (((s * 4 + l4) ^ (rn & 7)) << 3)]);
        }
#pragma unroll
        for (int mi = 0; mi < 4; ++mi)
#pragma unroll
          for (int ni = 0; ni < 4; ++ni)
            acc[mi][ni] = __builtin_amdgcn_mfma_f32_16x16x32_bf16(af[mi], bfr[ni], acc[mi][ni], 0, 0, 0);
      }
    }
  }
  int colB = wn + l15;
  int rowB = wm + l4 * 4;
#pragma unroll
  for (int ni = 0; ni < 4; ++ni) {
    int oc = nh * 128 + colB + ni * 16;
    float bv = bias[oc];
#pragma unroll
    for (int mi = 0; mi < 4; ++mi) {
#pragma unroll
      for (int r = 0; r < 4; ++r) {
        int pix = rowB + mi * 16 + r;
        out[((size_t)(b * NN + h * WWI + pix)) * CC + oc] = f2b(acc[mi][ni][r] + bv);
      }
    }
  }
}

// ---------- z-batched MFMA GEMM, outf += acc + bias; async global_load_lds staging ----------
__global__ __launch_bounds__(256, 2) void gemm_acc_kernel(
    const bf16* __restrict__ A, const bf16* __restrict__ BT,
    const float* __restrict__ bias, float* __restrict__ outf,
    int M, int N, int K, size_t strideAz, size_t strideBz, size_t strideOz) {
  A  += (size_t)blockIdx.z * strideAz;
  BT += (size_t)blockIdx.z * strideBz;
  __shared__ __align__(16) unsigned short As[128 * 64];   // 16 KiB
  __shared__ __align__(16) unsigned short Bs[128 * 64];   // 16 KiB
  int m0 = blockIdx.x * 128, n0 = blockIdx.y * 128;
  int t = threadIdx.x, lane = t & 63, wid = t >> 6;
  int wm = (wid >> 1) * 64, wn = (wid & 1) * 64;
  int l15 = lane & 15, q4 = lane >> 4;
  int wg = wm >> 4, ng = wn >> 4;
  f32x4 acc[4][4];
#pragma unroll
  for (int mi = 0; mi < 4; ++mi)
#pragma unroll
    for (int ni = 0; ni < 4; ++ni) acc[mi][ni] = (f32x4){0.f, 0.f, 0.f, 0.f};

  for (int kb = 0; kb < K; kb += 64) {
    __syncthreads();
#pragma unroll
    for (int i = 0; i < 4; ++i) {
      int inst = wid * 4 + i;
      int g = inst >> 1, h2 = inst & 1;
      int row = g * 16 + l15;
      int kc = (h2 * 4 + q4) * 8;
      async16(&As[(size_t)g * 1024 + h2 * 512], A + (size_t)(m0 + row) * K + kb + kc);
      async16(&Bs[(size_t)g * 1024 + h2 * 512], BT + (size_t)(n0 + row) * K + kb + kc);
    }
    __syncthreads();
#pragma unroll
    for (int s = 0; s < 2; ++s) {
      int kgrp = s * 4 + q4;
      bfv8 af[4], bfr[4];
#pragma unroll
      for (int mi = 0; mi < 4; ++mi)
        af[mi] = *(const bfv8*)(&As[(size_t)(wg + mi) * 1024 + kgrp * 128 + l15 * 8]);
#pragma unroll
      for (int ni = 0; ni < 4; ++ni)
        bfr[ni] = *(const bfv8*)(&Bs[(size_t)(ng + ni) * 1024 + kgrp * 128 + l15 * 8]);
#pragma unroll
      for (int mi = 0; mi < 4; ++mi)
#pragma unroll
        for (int ni = 0; ni < 4; ++ni)
          acc[mi][ni] = __builtin_amdgcn_mfma_f32_16x16x32_bf16(af[mi], bfr[ni], acc[mi][ni], 0, 0, 0);
    }
  }
  int colB = n0 + wn + l15;
  int rowB = m0 + wm + q4 * 4;
#pragma unroll
  for (int ni = 0; ni < 4; ++ni) {
    int col = colB + ni * 16;
    float bv = bias[col];
#pragma unroll
    for (int mi = 0; mi < 4; ++mi) {
#pragma unroll
      for (int r = 0; r < 4; ++r) {
        int row = rowB + mi * 16 + r;
        outf[(size_t)blockIdx.z * strideOz + (size_t)row * N + col] += acc[mi][ni][r] + bv;
      }
    }
  }
}

// ---------- fused MLP: fx += gelu(xln@w1+b1)@w2+b2 ----------
// M-tile 64, 512 threads / 8 waves, LDS 80 KiB -> 2 blocks/CU (4 waves/SIMD).
// All MFMA operands from LDS; W staged cooperatively per k-chunk.
__global__ __launch_bounds__(512, 4) void mlp_fused_kernel(
    const bf16* __restrict__ xln, const bf16* __restrict__ w1t,
    const float* __restrict__ b1, const bf16* __restrict__ w2t,
    const float* __restrict__ b2, float* __restrict__ fx) {
  __shared__ __align__(16) unsigned short As[64 * 256];   // 32 KiB (per-64 XOR swizzle)
  __shared__ __align__(16) bf16 Hs[64 * 128];             // 16 KiB
  __shared__ __align__(16) unsigned short Wb[256 * 64];   // 32 KiB weight staging
  int m0 = blockIdx.x * 64;
  int t = threadIdx.x, lane = t & 63, wid = t >> 6;       // wid 0..7
  int l15 = lane & 15, q4 = lane >> 4;
  // GEMM1: 64m x 128n -> 2x4 wave grid of 32m x 32n
  int wm2 = (wid & 1) * 32, wn2 = (wid >> 1) * 32;
  // GEMM2: 64m x 256n -> 2x4 wave grid of 32m x 64n
  int wm = (wid & 1) * 32, wn = (wid >> 1) * 64;

  // stage A (xln rows m0..m0+63, full K=256) — once
  const unsigned short* xg = (const unsigned short*)xln + (size_t)m0 * 256;
#pragma unroll
  for (int i = 0; i < 4; ++i) {
    int u = t + i * 512;                  // 2048 vec writes
    int row = u >> 5, v = u & 31;
    int kb = v >> 3, jp = v & 7;
    uint4 val = ((const uint4*)xg)[u];
    ((uint4*)As)[row * 32 + kb * 8 + (jp ^ (row & 7))] = val;
  }

  f32x4 accO[2][4];
#pragma unroll
  for (int mi = 0; mi < 2; ++mi)
#pragma unroll
    for (int ni = 0; ni < 4; ++ni) accO[mi][ni] = (f32x4){0.f, 0.f, 0.f, 0.f};

  for (int j = 0; j < 8; ++j) {           // hidden chunks of 128
    int hbase = j * 128;
    f32x4 acc2[2][2];
#pragma unroll
    for (int mi = 0; mi < 2; ++mi)
#pragma unroll
      for (int nj = 0; nj < 2; ++nj) acc2[mi][nj] = (f32x4){0.f, 0.f, 0.f, 0.f};
    // ---- GEMM1: hidden chunk = A(LDS) @ W1[:, hbase:hbase+128] ----
    for (int kb = 0; kb < 4; ++kb) {
      __syncthreads();
#pragma unroll
      for (int i = 0; i < 2; ++i) {       // stage W1T chunk [128 n][64 k] = 16 KiB
        int u = t + i * 512;
        int n = u >> 3, jp = u & 7;
        uint4 val = *(const uint4*)(w1t + (size_t)(hbase + n) * 256 + kb * 64 + jp * 8);
        ((uint4*)Wb)[n * 8 + (jp ^ (n & 7))] = val;
      }
      __syncthreads();
#pragma unroll
      for (int ks = 0; ks < 2; ++ks) {
        int kgrp = ks * 4 + q4;
        bfv8 af[2], bfr[2];
#pragma unroll
        for (int mi = 0; mi < 2; ++mi) {
          int row = wm2 + mi * 16 + l15;
          af[mi] = *(const bfv8*)(&As[row * 256 + kb * 64 + ((kgrp ^ (row & 7)) << 3)]);
        }
#pragma unroll
        for (int nj = 0; nj < 2; ++nj) {
          int n = wn2 + nj * 16 + l15;
          bfr[nj] = *(const bfv8*)(&Wb[n * 64 + ((kgrp ^ (n & 7)) << 3)]);
        }
#pragma unroll
        for (int mi = 0; mi < 2; ++mi)
#pragma unroll
          for (int nj = 0; nj < 2; ++nj)
            acc2[mi][nj] = __builtin_amdgcn_mfma_f32_16x16x32_bf16(af[mi], bfr[nj], acc2[mi][nj], 0, 0, 0);
      }
    }
    // ---- +b1, gelu, pack to Hs (bf16) ----
#pragma unroll
    for (int nj = 0; nj < 2; ++nj) {
      int coln = wn2 + nj * 16 + l15;
      float bv = b1[hbase + coln];
      int half = coln >> 6, sub = (coln >> 3) & 7, lo = coln & 7;
#pragma unroll
      for (int mi = 0; mi < 2; ++mi) {
#pragma unroll
        for (int r = 0; r < 4; ++r) {
          int row = wm2 + mi * 16 + q4 * 4 + r;
          float v = acc2[mi][nj][r] + bv;
          Hs[row * 128 + half * 64 + (((sub ^ (row & 7)) << 3) + lo)] = f2b(gelu_exact(v));
        }
      }
    }
    // ---- GEMM2: out += H(LDS) @ W2[hbase:hbase+128, :] ----
    for (int kb2 = 0; kb2 < 2; ++kb2) {
      __syncthreads();                    // Hs visible (first iter); Wb free
#pragma unroll
      for (int i = 0; i < 4; ++i) {       // stage W2T chunk [256 n][64 k] = 32 KiB
        int u = t + i * 512;
        int n = u >> 3, jp = u & 7;
        uint4 val = *(const uint4*)(w2t + (size_t)n * 1024 + hbase + kb2 * 64 + jp * 8);
        ((uint4*)Wb)[n * 8 + (jp ^ (n & 7))] = val;
      }
      __syncthreads();
#pragma unroll
      for (int ks = 0; ks < 2; ++ks) {
        int kgrp = ks * 4 + q4;
        bfv8 af[2], bfr[4];
#pragma unroll
        for (int mi = 0; mi < 2; ++mi) {
          int row = wm + mi * 16 + l15;
          af[mi] = *(const bfv8*)(&Hs[row * 128 + kb2 * 64 + ((kgrp ^ (row & 7)) << 3)]);
        }
#pragma unroll
        for (int ni = 0; ni < 4; ++ni) {
          int n = wn + ni * 16 + l15;
          bfr[ni] = *(const bfv8*)(&Wb[n * 64 + ((kgrp ^ (n & 7)) << 3)]);
        }
#pragma unroll
        for (int mi = 0; mi < 2; ++mi)
#pragma unroll
          for (int ni = 0; ni < 4; ++ni)
            accO[mi][ni] = __builtin_amdgcn_mfma_f32_16x16x32_bf16(af[mi], bfr[ni], accO[mi][ni], 0, 0, 0);
      }
    }
  }
  // ---- epilogue: fx += accO + b2 ----
#pragma unroll
  for (int ni = 0; ni < 4; ++ni) {
    int col = wn + ni * 16 + l15;
    float bv = b2[col];
#pragma unroll
    for (int mi = 0; mi < 2; ++mi) {
#pragma unroll
      for (int r = 0; r < 4; ++r) {
        int row = m0 + wm + mi * 16 + q4 * 4 + r;
        fx[(size_t)row * 256 + col] += accO[mi][ni][r] + bv;
      }
    }
  }
}

// ---------- slice logits + softmax over G; 16 points/block, weights in LDS ----------
__global__ __launch_bounds__(256) void slice_softmax_kernel(
    const bf16* __restrict__ xmid, const float* __restrict__ sw_w,
    const float* __restrict__ sw_b, const float* __restrict__ temp,
    bf16* __restrict__ swout) {
  __shared__ float wsm[32][64];     // 8 KiB  [d][g]
  __shared__ float xm[SSP][256];    // 16 KiB
  __shared__ float bias_s[64];
  __shared__ float rtc[8];
  int p0 = blockIdx.x * SSP;
  int t = threadIdx.x;
  for (int i = t; i < 2048; i += 256) wsm[i >> 6][i & 63] = sw_w[i];
  if (t < 64) bias_s[t] = sw_b[t];
  if (t < 8) {
    float x = temp[t];
    rtc[t] = 1.0f / fminf(fmaxf(x, 0.1f), 5.0f);
  }
  const unsigned short* xg = (const unsigned short*)xmid + (size_t)p0 * 256;
#pragma unroll
  for (int i2 = t; i2 < SSP * 32; i2 += 256) {
    uint4 v = ((const uint4*)xg)[i2];
    int p = i2 >> 5, c = (i2 & 31) << 3;
    xm[p][c + 0] = us2f((unsigned short)(v.x & 0xffff));
    xm[p][c + 1] = us2f((unsigned short)(v.x >> 16));
    xm[p][c + 2] = us2f((unsigned short)(v.y & 0xffff));
    xm[p][c + 3] = us2f((unsigned short)(v.y >> 16));
    xm[p][c + 4] = us2f((unsigned short)(v.z & 0xffff));
    xm[p][c + 5] = us2f((unsigned short)(v.z >> 16));
    xm[p][c + 6] = us2f((unsigned short)(v.w & 0xffff));
    xm[p][c + 7] = us2f((unsigned short)(v.w >> 16));
  }
  __syncthreads();
  int g = t & 63, pq = t >> 6;
  for (int pp2 = 0; pp2 < SSP / 4; ++pp2) {
    int p = pp2 * 4 + pq;
#pragma unroll
    for (int h = 0; h < NHEADS; ++h) {
      float acc = bias_s[g];
      const float* xr = &xm[p][h * 32];
#pragma unroll
      for (int d = 0; d < 32; ++d) acc += xr[d] * wsm[d][g];
      float logit = acc * rtc[h];
      float m = logit;
#pragma unroll
      for (int off = 32; off > 0; off >>= 1) m = fmaxf(m, __shfl_xor(m, off, 64));
      float e = __expf(logit - m);
      float s = e;
#pragma unroll
      for (int off = 32; off > 0; off >>= 1) s += __shfl_xor(s, off, 64);
      swout[(size_t)(p0 + p) * 512 + h * 64 + g] = f2b(e / s);
    }
  }
}

// ---------- slice reduce as split-K MFMA outer product ----------
__global__ __launch_bounds__(256) void slice_st_kernel(
    const bf16* __restrict__ fxmid, const bf16* __restrict__ sw,
    float* __restrict__ stp, float* __restrict__ normp) {
  __shared__ __align__(16) unsigned short sw_s[64 * 64];
  __shared__ __align__(16) unsigned short fx_s[32 * 64];
  __shared__ float npart[2][64];
  int split = blockIdx.x, h = blockIdx.y, b = blockIdx.z;
  int t = threadIdx.x, w = t >> 6, lane = t & 63;
  int l15 = lane & 15, q4 = lane >> 4;
  int ns0 = split * (NN / SPLIT);
  const int NT = (NN / SPLIT) / 64;
  f32x4 acc0 = {0.f, 0.f, 0.f, 0.f}, acc1 = {0.f, 0.f, 0.f, 0.f};
  float nacc = 0.f;
  const unsigned short* swg = (const unsigned short*)sw + (size_t)b * NN * 512 + h * 64;
  const unsigned short* fxg = (const unsigned short*)fxmid + (size_t)b * NN * 256 + h * 32;

  for (int kt = 0; kt < NT; ++kt) {
    int n0 = ns0 + kt * 64;
    __syncthreads();
    if (w < 2) {
      int g = lane;
#pragma unroll
      for (int i = 0; i < 4; ++i) {
        int j = w + 2 * i;
        const unsigned short* p = swg + (size_t)(n0 + j * 8) * 512 + g;
        unsigned short v0 = p[0],     v1 = p[512],  v2 = p[1024], v3 = p[1536];
        unsigned short v4 = p[2048],  v5 = p[2560], v6 = p[3072], v7 = p[3584];
        nacc += us2f(v0) + us2f(v1) + us2f(v2) + us2f(v3) +
                us2f(v4) + us2f(v5) + us2f(v6) + us2f(v7);
        uint4 pk = make_uint4((unsigned)v0 | ((unsigned)v1 << 16),
                              (unsigned)v2 | ((unsigned)v3 << 16),
                              (unsigned)v4 | ((unsigned)v5 << 16),
                              (unsigned)v6 | ((unsigned)v7 << 16));
        ((uint4*)sw_s)[g * 8 + (j ^ (g & 7))] = pk;
      }
    } else {
      int d = lane & 31, nh = lane >> 5, w3 = w - 2;
#pragma unroll
      for (int i = 0; i < 2; ++i) {
        int nbase = (w3 * 2 + i) * 16 + nh * 8;
        const unsigned short* p = fxg + (size_t)(n0 + nbase) * 256 + d;
        unsigned short v0 = p[0],    v1 = p[256],  v2 = p[512],  v3 = p[768];
        unsigned short v4 = p[1024], v5 = p[1280], v6 = p[1536], v7 = p[1792];
        uint4 pk = make_uint4((unsigned)v0 | ((unsigned)v1 << 16),
                              (unsigned)v2 | ((unsigned)v3 << 16),
                              (unsigned)v4 | ((unsigned)v5 << 16),
                              (unsigned)v6 | ((unsigned)v7 << 16));
        int u = nbase >> 3;
        ((uint4*)fx_s)[d * 8 + (u ^ (d & 7))] = pk;
      }
    }
    __syncthreads();
    int gg = w * 16 + l15;
    int d0 = l15, d1 = 16 + l15;
#pragma unroll
    for (int ks = 0; ks < 2; ++ks) {
      bfv8 af  = ((const bfv8*)sw_s)[gg * 8 + ((ks * 4 + q4) ^ (gg & 7))];
      bfv8 bf0 = ((const bfv8*)fx_s)[d0 * 8 + ((ks * 4 + q4) ^ (d0 & 7))];
      bfv8 bf1 = ((const bfv8*)fx_s)[d1 * 8 + ((ks * 4 + q4) ^ (d1 & 7))];
      acc0 = __builtin_amdgcn_mfma_f32_16x16x32_bf16(af, bf0, acc0, 0, 0, 0);
      acc1 = __builtin_amdgcn_mfma_f32_16x16x32_bf16(af, bf1, acc1, 0, 0, 0);
    }
  }
  if (w < 2) npart[w][lane] = nacc;
  __syncthreads();
  int bh = b * NHEADS + h;
  if (t < 64) normp[(size_t)split * (BB * NHEADS * GG) + bh * 64 + t] = npart[0][t] + npart[1][t];
  size_t base = ((size_t)split * (BB * NHEADS * GG) + bh * 64) * 32;
#pragma unroll
  for (int r = 0; r < 4; ++r) {
    int g = w * 16 + q4 * 4 + r;
    stp[base + (size_t)g * 32 + l15] = acc0[r];
    stp[base + (size_t)g * 32 + 16 + l15] = acc1[r];
  }
}

// ---------- attention over G=64 per (b,h); 256 threads; weights + reduction in LDS ----------
__global__ __launch_bounds__(256) void attn_kernel(
    const float* __restrict__ stp, const float* __restrict__ normp,
    const float* __restrict__ wq, const float* __restrict__ wk,
    const float* __restrict__ wv, float* __restrict__ ot) {
  __shared__ float wqs[32 * 32], wks[32 * 32], wvs[32 * 32];
  __shared__ float st[GG][DHD + 1];
  __shared__ float qq[GG][DHD + 1], kk[GG][DHD + 1], vv[GG][DHD + 1];
  __shared__ float pm[GG][GG + 1];
  __shared__ float nrm[GG];
  int bh = blockIdx.x;
  int t = threadIdx.x;
  ((float4*)wqs)[t] = ((const float4*)wq)[t];
  ((float4*)wks)[t] = ((const float4*)wk)[t];
  ((float4*)wvs)[t] = ((const float4*)wv)[t];
  if (t < 64) {
    float ns = 0.f;
    for (int s = 0; s < SPLIT; ++s) ns += normp[(size_t)s * (BB * NHEADS * GG) + bh * 64 + t];
    nrm[t] = 1.0f / (ns + 1e-5f);
  }
  __syncthreads();
#pragma unroll
  for (int i = 0; i < 8; ++i) {
    int idx = t + i * 256;
    int g = idx >> 5, d = idx & 31;
    float a = 0.f;
    for (int s = 0; s < SPLIT; ++s)
      a += stp[((size_t)s * (BB * NHEADS * GG) + bh * 64 + g) * 32 + d];
    st[g][d] = a * nrm[g];
  }
  __syncthreads();
#pragma unroll
  for (int i = 0; i < 8; ++i) {
    int idx = t + i * 256;
    int g = idx >> 5, d = idx & 31;
    float aq = 0.f, ak = 0.f, av = 0.f;
#pragma unroll
    for (int c = 0; c < 32; ++c) {
      float sv = st[g][c];
      aq += sv * wqs[c * 32 + d];
      ak += sv * wks[c * 32 + d];
      av += sv * wvs[c * 32 + d];
    }
    qq[g][d] = aq; kk[g][d] = ak; vv[g][d] = av;
  }
  __syncthreads();
  {
    int g = t >> 2, sub = t & 3;
    float sc[16];
    float m = -1e30f;
    const float scale = 0.17677669529663687f;
#pragma unroll
    for (int jj = 0; jj < 16; ++jj) {
      int j = sub * 16 + jj;
      float a = 0.f;
#pragma unroll
      for (int d = 0; d < 32; ++d) a += qq[g][d] * kk[j][d];
      a *= scale;
      sc[jj] = a;
      m = fmaxf(m, a);
    }
    m = fmaxf(m, __shfl_xor(m, 1, 64));
    m = fmaxf(m, __shfl_xor(m, 2, 64));
    float ssum = 0.f;
#pragma unroll
    for (int jj = 0; jj < 16; ++jj) { sc[jj] = __expf(sc[jj] - m); ssum += sc[jj]; }
    ssum += __shfl_xor(ssum, 1, 64);
    ssum += __shfl_xor(ssum, 2, 64);
    float rs = 1.0f / ssum;
#pragma unroll
    for (int jj = 0; jj < 16; ++jj) pm[g][sub * 16 + jj] = sc[jj] * rs;
  }
  __syncthreads();
#pragma unroll
  for (int i = 0; i < 8; ++i) {
    int idx = t + i * 256;
    int g = idx >> 5, d = idx & 31;
    float a = 0.f;
#pragma unroll
    for (int j = 0; j < GG; ++j) a += pm[g][j] * vv[j][d];
    ot[((size_t)bh * GG + g) * DHD + d] = a;
  }
}

// ---------- Wc^T[b][c][h*64+g] = sum_d ot[b,h,g,d] * wo[h*32+d, c]  (bf16 out) ----------
__global__ __launch_bounds__(256) void wc_kernel(const float* __restrict__ ot,
                                                 const float* __restrict__ wo,
                                                 bf16* __restrict__ wct) {
  __shared__ float ots[GG][DHD];   // 8 KiB
  int bh = blockIdx.x;             // b*8 + h
  int h = bh & 7, b = bh >> 3;
  int t = threadIdx.x;             // 256 = c
  for (int i = t; i < GG * DHD; i += 256) ots[i >> 5][i & 31] = ot[(size_t)bh * (GG * DHD) + i];
  float wol[DHD];
#pragma unroll
  for (int d = 0; d < DHD; ++d) wol[d] = wo[(size_t)(h * DHD + d) * CC + t];
  __syncthreads();
  bf16* dst = wct + ((size_t)b * CC + t) * (NHEADS * GG) + h * GG;
#pragma unroll 4
  for (int g = 0; g < GG; ++g) {
    float a = 0.f;
#pragma unroll
    for (int d = 0; d < DHD; ++d) a += wol[d] * ots[g][d];
    dst[g] = f2b(a);
  }
}

// ---------- final LN3 + head (C -> 4) ----------
__global__ void head_kernel(const float* __restrict__ fx, const float* __restrict__ w,
                            const float* __restrict__ b, const float* __restrict__ wout,
                            const float* __restrict__ bout, float* __restrict__ out) {
  int pp = blockIdx.x;
  int t = threadIdx.x;
  float v = fx[(size_t)pp * CC + t];
  float s = wave_sum(v);
  float sq = wave_sum(v * v);
  __shared__ float ls[4], lq[4];
  int wid = t >> 6, lane = t & 63;
  if (lane == 0) { ls[wid] = s; lq[wid] = sq; }
  __syncthreads();
  float tot = ls[0] + ls[1] + ls[2] + ls[3];
  float totq = lq[0] + lq[1] + lq[2] + lq[3];
  float mean = tot * (1.0f / CC);
  float var = totq * (1.0f / CC) - mean * mean;
  float rstd = rsqrtf(var + 1e-5f);
  float xn = (v - mean) * rstd * w[t] + b[t];
  __shared__ float xs[CC];
  xs[t] = xn;
  __syncthreads();
  if (t < 4) {
    float a = bout[t];
    for (int c = 0; c < CC; ++c) a += xs[c] * wout[c * 4 + t];
    out[(size_t)pp * 4 + t] = a;
  }
}

extern "C" void kernel_launch(void* const* d_in, const int* in_sizes, int n_in,
                              void* d_out, int out_size, void* d_ws, size_t ws_size,
                              hipStream_t stream) {
  const float* fx_in      = (const float*)d_in[0];
  const float* ln1_w      = (const float*)d_in[1];
  const float* ln1_b      = (const float*)d_in[2];
  const float* convx_w    = (const float*)d_in[3];
  const float* convx_b    = (const float*)d_in[4];
  const float* convfx_w   = (const float*)d_in[5];
  const float* convfx_b   = (const float*)d_in[6];
  const float* slice_w    = (const float*)d_in[7];
  const float* slice_b    = (const float*)d_in[8];
  const float* temperature= (const float*)d_in[9];
  const float* wq         = (const float*)d_in[10];
  const float* wk         = (const float*)d_in[11];
  const float* wv         = (const float*)d_in[12];
  const float* wo         = (const float*)d_in[13];
  const float* bo         = (const float*)d_in[14];
  const float* ln2_w      = (const float*)d_in[15];
  const float* ln2_b      = (const float*)d_in[16];
  const float* w1         = (const float*)d_in[17];
  const float* b1         = (const float*)d_in[18];
  const float* w2         = (const float*)d_in[19];
  const float* b2         = (const float*)d_in[20];
  const float* ln3_w      = (const float*)d_in[21];
  const float* ln3_b      = (const float*)d_in[22];
  const float* w_out      = (const float*)d_in[23];
  const float* b_out      = (const float*)d_in[24];
  float* out = (float*)d_out;

  char* ws = (char*)d_ws;
  size_t off = 0;
  auto alloc = [&](size_t bytes) -> void* {
    void* p = ws + off;
    off += (bytes + 255) & ~(size_t)255;
    return p;
  };
  float* fx32  = (float*)alloc((size_t)BB * NN * CC * 4);    // 64 MiB
  bf16* xln    = (bf16*)alloc((size_t)BB * NN * CC * 2);     // 32 MiB
  char* uni    = (char*)alloc((size_t)BB * NN * 512 * 2 * 2);// xmid/fxmid/swb region
  bf16* xmid   = (bf16*)uni;
  bf16* fxmid  = (bf16*)(uni + (size_t)BB * NN * INNERC * 2);
  bf16* swb    = (bf16*)(uni + (size_t)2 * BB * NN * INNERC * 2);
  float* stp   = (float*)uni;                                // 8 MiB (aliases dead xmid)
  float* normp = (float*)(uni + (size_t)SPLIT * BB * NHEADS * GG * DHD * 4);
  bf16* wtx    = (bf16*)alloc((size_t)LL * 9 * CC * INNERC * 2);
  bf16* wtfx   = (bf16*)alloc((size_t)LL * 9 * CC * INNERC * 2);
  bf16* w1t    = (bf16*)alloc((size_t)LL * CC * HIDD * 2);
  bf16* w2t    = (bf16*)alloc((size_t)LL * HIDD * CC * 2);
  float* otb   = (float*)alloc((size_t)BB * NHEADS * GG * DHD * 4);
  bf16* wct    = (bf16*)alloc((size_t)BB * CC * NHEADS * GG * 2);   // 1 MiB
  (void)ws_size; (void)in_sizes; (void)n_in; (void)out_size;

  transpose_cast_kernel<<<dim3(8, 8, LL * 9), 256, 0, stream>>>(convx_w, wtx, CC, INNERC);
  transpose_cast_kernel<<<dim3(8, 8, LL * 9), 256, 0, stream>>>(convfx_w, wtfx, CC, INNERC);
  transpose_cast_kernel<<<dim3(32, 8, LL), 256, 0, stream>>>(w1, w1t, CC, HIDD);
  transpose_cast_kernel<<<dim3(8, 32, LL), 256, 0, stream>>>(w2, w2t, HIDD, CC);

  hipMemcpyAsync(fx32, fx_in, (size_t)BB * NN * CC * sizeof(float),
                 hipMemcpyDeviceToDevice, stream);

  const int M = BB * NN;  // 65536
  for (int i = 0; i < LL; ++i) {
    ln_kernel<<<M, 256, 0, stream>>>(fx32, ln1_w + i * CC, ln1_b + i * CC, xln);
    conv_mfma_kernel<<<BB * HH * 2, 256, 0, stream>>>(
        xln, wtfx + (size_t)i * 9 * CC * INNERC, convfx_b + i * INNERC, fxmid);
    conv_mfma_kernel<<<BB * HH * 2, 256, 0, stream>>>(
        xln, wtx + (size_t)i * 9 * CC * INNERC, convx_b + i * INNERC, xmid);
    slice_softmax_kernel<<<M / SSP, 256, 0, stream>>>(
        xmid, slice_w + i * DHD * GG, slice_b + i * GG, temperature + i * NHEADS, swb);
    slice_st_kernel<<<dim3(SPLIT, NHEADS, BB), 256, 0, stream>>>(fxmid, swb, stp, normp);
    attn_kernel<<<BB * NHEADS, 256, 0, stream>>>(
        stp, normp, wq + i * DHD * DHD, wk + i * DHD * DHD, wv + i * DHD * DHD, otb);
    wc_kernel<<<BB * NHEADS, 256, 0, stream>>>(otb, wo + (size_t)i * INNERC * CC, wct);
    // fx[b] += sw[b] @ Wc[b] + bo   (deslice + wo-projection fused)
    gemm_acc_kernel<<<dim3(NN / 128, CC / 128, BB), 256, 0, stream>>>(
        swb, wct, bo + i * CC, fx32, NN, CC, NHEADS * GG,
        (size_t)NN * (NHEADS * GG), (size_t)CC * (NHEADS * GG), (size_t)NN * CC);
    ln_kernel<<<M, 256, 0, stream>>>(fx32, ln2_w + i * CC, ln2_b + i * CC, xln);
    mlp_fused_kernel<<<M / 64, 512, 0, stream>>>(
        xln, w1t + (size_t)i * CC * HIDD, b1 + i * HIDD,
        w2t + (size_t)i * HIDD * CC, b2 + i * CC, fx32);
  }
  head_kernel<<<M, 256, 0, stream>>>(fx32, ln3_w, ln3_b, w_out, b_out, out);
}